// Round 9
// baseline (349.614 us; speedup 1.0000x reference)
//
#include <hip/hip_runtime.h>
#include <math.h>
#include <stdint.h>

// Problem constants
#define D 768
#define S 2048
#define B_ 2
#define NROWS 4096   // B_*S
#define H 12
#define HD 64
#define R_ 16

typedef _Float16 half_t;
typedef _Float16 half8 __attribute__((ext_vector_type(8)));
typedef _Float16 half4 __attribute__((ext_vector_type(4)));
typedef float floatx4 __attribute__((ext_vector_type(4)));

#define MFMA32(a, b, c) __builtin_amdgcn_mfma_f32_16x16x32_f16(a, b, c, 0, 0, 0)
#define MFMA16(a, b, c) __builtin_amdgcn_mfma_f32_16x16x16f16(a, b, c, 0, 0, 0)
#define EXP2F(x) __builtin_amdgcn_exp2f(x)

// global -> LDS async DMA, 16B per lane; lane i lands at base + 16*i.
__device__ __forceinline__ void gl_lds16(const void* gp, half_t* lp) {
  __builtin_amdgcn_global_load_lds(
      (const __attribute__((address_space(1))) void*)(gp),
      (__attribute__((address_space(3))) void*)(lp), 16, 0, 0);
}

// ---------------------------------------------------------------------------
// Fused prep: blocks [0, 9216): fp32->fp16 convert of q,k,v.
//             blocks [9216, 18432): build folded LoRA weights
//             Mh[j][k] = W[j][k] + 4*sum_r A[k,r]A[j,r]  (fp16, [j][k]).
// ---------------------------------------------------------------------------
__global__ __launch_bounds__(256) void prep_kernel(
    const float* __restrict__ q, const float* __restrict__ k,
    const float* __restrict__ v, half_t* __restrict__ xq,
    half_t* __restrict__ xk, half_t* __restrict__ xv,
    const float* __restrict__ Wq, const float* __restrict__ Aq,
    const float* __restrict__ Wk, const float* __restrict__ Ak,
    const float* __restrict__ Wv, const float* __restrict__ Av,
    const float* __restrict__ Wo, half_t* __restrict__ Mq,
    half_t* __restrict__ Mk, half_t* __restrict__ Mv,
    half_t* __restrict__ Mo) {
  const int bid = blockIdx.x;
  if (bid < 9216) {
    const int y = bid / 3072;
    const float* x = (y == 0) ? q : (y == 1) ? k : v;
    half_t* o = (y == 0) ? xq : (y == 1) ? xk : xv;
    int i = (bid - y * 3072) * 1024 + threadIdx.x * 4;
    float4 vv = *reinterpret_cast<const float4*>(x + i);
    half_t tmp[4] = {(half_t)vv.x, (half_t)vv.y, (half_t)vv.z, (half_t)vv.w};
    *reinterpret_cast<uint64_t*>(o + i) = *reinterpret_cast<uint64_t*>(tmp);
  } else {
    const int u = bid - 9216;
    const int y = u / 2304;
    const float* W = (y == 0) ? Wq : (y == 1) ? Wk : (y == 2) ? Wv : Wo;
    const float* A = (y == 0) ? Aq : (y == 1) ? Ak : (y == 2) ? Av : nullptr;
    half_t* M = (y == 0) ? Mq : (y == 1) ? Mk : (y == 2) ? Mv : Mo;
    int idx = (u - y * 2304) * 256 + threadIdx.x;  // j*768 + k
    int j = idx / D;
    int kk = idx - j * D;
    float acc = W[idx];
    if (A != nullptr) {
      float s = 0.f;
#pragma unroll
      for (int r = 0; r < R_; ++r) s += A[kk * R_ + r] * A[j * R_ + r];
      acc += 4.0f * s;
    }
    M[idx] = (half_t)acc;
  }
}

// ---------------------------------------------------------------------------
// QKV GEMM (fp16 in/out): C[n][j] = sum_k X[n][k]*Mh[j][k] + bias[j].
// 64x128 tile, 4 waves (1x4). A: DMA->LDS double-buffered (16KB).
// B: global->registers double-buffered (M is L2-resident). One barrier/iter.
// z==2 writes V output TRANSPOSED per head: vt[(b*H+h)*HD+d][s].
// ---------------------------------------------------------------------------
__global__ __launch_bounds__(256) void gemm_qkv_kernel(
    const half_t* __restrict__ x0, const half_t* __restrict__ x1,
    const half_t* __restrict__ x2, const half_t* __restrict__ m0,
    const half_t* __restrict__ m1, const half_t* __restrict__ m2,
    const float* __restrict__ b0, const float* __restrict__ b1,
    const float* __restrict__ b2, half_t* __restrict__ o0,
    half_t* __restrict__ o1, half_t* __restrict__ o2) {
  constexpr int TRS = 72;  // V-transpose stride (halfs, %8==0)
  // staging: 2 buffers x 8 A-groups x 512 halfs = 8192; transpose needs 9216.
  __shared__ __align__(16) half_t smem[9216];  // 18KB

  const int z = blockIdx.z;
  const half_t* X = (z == 0) ? x0 : (z == 1) ? x1 : x2;
  const half_t* M = (z == 0) ? m0 : (z == 1) ? m1 : m2;
  const float* bias = (z == 0) ? b0 : (z == 1) ? b1 : b2;
  half_t* Out = (z == 0) ? o0 : (z == 1) ? o1 : o2;

  const int tid = threadIdx.x;
  const int lane = tid & 63;
  const int wv = tid >> 6;
  const int lr = lane & 15;
  const int lq = lane >> 4;
  const int row0 = blockIdx.y * 64;
  const int j0 = blockIdx.x * 128;
  const int wc = wv;  // 1x4 wave grid, 32 cols per wave

  floatx4 acc[4][2] = {};
  half8 bA[2][2], bB[2][2];  // [u][c] register double-buffer for B

#define STAGEA(bufi, k0)                                                       \
  do {                                                                         \
    _Pragma("unroll") for (int gi = 0; gi < 2; ++gi) {                         \
      int g = wv * 2 + gi;                                                     \
      int t = g >> 1, c = g & 1;                                               \
      gl_lds16(X + (size_t)(row0 + t * 16 + lr) * D + (k0) + c * 32 + lq * 8,  \
               smem + (bufi)*4096 + g * 512);                                  \
    }                                                                          \
  } while (0)

#define LOADB(BF, k0)                                                          \
  do {                                                                         \
    _Pragma("unroll") for (int u = 0; u < 2; ++u)                              \
        _Pragma("unroll") for (int c = 0; c < 2; ++c) BF[u][c] =               \
        *reinterpret_cast<const half8*>(                                       \
            &M[(size_t)(j0 + (wc * 2 + u) * 16 + lr) * D + (k0) + c * 32 +     \
               lq * 8]);                                                       \
  } while (0)

#define COMPUTEG(BF, bufi)                                                     \
  do {                                                                         \
    _Pragma("unroll") for (int c = 0; c < 2; ++c) {                            \
      half8 af[4];                                                             \
      _Pragma("unroll") for (int t = 0; t < 4; ++t) af[t] =                    \
          *reinterpret_cast<const half8*>(                                     \
              &smem[(bufi)*4096 + ((t * 2 + c) * 64 + lane) * 8]);             \
      _Pragma("unroll") for (int t = 0; t < 4; ++t)                            \
          _Pragma("unroll") for (int u = 0; u < 2; ++u) acc[t][u] =            \
          MFMA32(af[t], BF[u][c], acc[t][u]);                                  \
    }                                                                          \
  } while (0)

  STAGEA(0, 0);
  LOADB(bA, 0);
  __syncthreads();

#pragma unroll 1
  for (int it = 0; it < D / 64; it += 2) {
    STAGEA(1, (it + 1) * 64);
    LOADB(bB, (it + 1) * 64);
    COMPUTEG(bA, 0);
    __syncthreads();
    if (it + 2 < D / 64) {
      STAGEA(0, (it + 2) * 64);
      LOADB(bA, (it + 2) * 64);
    }
    COMPUTEG(bB, 1);
    __syncthreads();
  }
#undef STAGEA
#undef LOADB
#undef COMPUTEG

  float bv[2];
#pragma unroll
  for (int u = 0; u < 2; ++u) bv[u] = bias[j0 + (wc * 2 + u) * 16 + lr];

  if (z == 2) {
    // transpose through LDS, emit V^T [b][h][d][S] coalesced
#pragma unroll
    for (int t = 0; t < 4; ++t) {
#pragma unroll
      for (int u = 0; u < 2; ++u) {
        int c_local = (wc * 2 + u) * 16 + lr;  // 0..127
#pragma unroll
        for (int r = 0; r < 4; ++r) {
          int r_local = t * 16 + lq * 4 + r;   // 0..63
          smem[c_local * TRS + r_local] = (half_t)(acc[t][u][r] + bv[u]);
        }
      }
    }
    __syncthreads();
    const int bb = row0 >> 11;
    const int s_base = row0 & 2047;
#pragma unroll
    for (int it = 0; it < 4; ++it) {
      int unit = it * 256 + tid;      // 0..1023
      int c_local = unit >> 3;        // channel 0..127
      int chunk = unit & 7;           // token chunk 0..7
      half8 vv =
          *reinterpret_cast<const half8*>(&smem[c_local * TRS + chunk * 8]);
      int gc = j0 + c_local;
      int hh = gc >> 6, dd = gc & 63;
      *reinterpret_cast<half8*>(
          &Out[((size_t)(bb * H + hh) * HD + dd) * S + s_base + chunk * 8]) = vv;
    }
    return;
  }

#pragma unroll
  for (int t = 0; t < 4; ++t) {
#pragma unroll
    for (int u = 0; u < 2; ++u) {
#pragma unroll
      for (int r = 0; r < 4; ++r) {
        int gr = row0 + t * 16 + lq * 4 + r;
        int gc = j0 + (wc * 2 + u) * 16 + lr;
        Out[(size_t)gr * D + gc] = (half_t)(acc[t][u][r] + bv[u]);
      }
    }
  }
}

// ---------------------------------------------------------------------------
// Out-projection GEMM (fp16 in, fp32 out): 64x64 tile, 4 waves (1x4, 16
// cols each). A: DMA->LDS dbuf; B: global->regs dbuf. grid 768 = 3/CU.
// ---------------------------------------------------------------------------
__global__ __launch_bounds__(256) void gemm_o_kernel(
    const half_t* __restrict__ Xh, const half_t* __restrict__ M,
    const float* __restrict__ bias, float* __restrict__ Out) {
  __shared__ __align__(16) half_t smem[8192];  // 16KB: 2 x 8 A-groups

  const int tid = threadIdx.x;
  const int lane = tid & 63;
  const int wv = tid >> 6;
  const int lr = lane & 15;
  const int lq = lane >> 4;
  const int row0 = blockIdx.y * 64;
  const int j0 = blockIdx.x * 64;
  const int wc = wv;  // 16 cols per wave

  floatx4 acc[4] = {};
  half8 bA[2], bB[2];  // [c]

#define STAGEA(bufi, k0)                                                       \
  do {                                                                         \
    _Pragma("unroll") for (int gi = 0; gi < 2; ++gi) {                         \
      int g = wv * 2 + gi;                                                     \
      int t = g >> 1, c = g & 1;                                               \
      gl_lds16(Xh + (size_t)(row0 + t * 16 + lr) * D + (k0) + c * 32 + lq * 8, \
               smem + (bufi)*4096 + g * 512);                                  \
    }                                                                          \
  } while (0)

#define LOADB(BF, k0)                                                          \
  do {                                                                         \
    _Pragma("unroll") for (int c = 0; c < 2; ++c) BF[c] =                      \
        *reinterpret_cast<const half8*>(                                       \
            &M[(size_t)(j0 + wc * 16 + lr) * D + (k0) + c * 32 + lq * 8]);     \
  } while (0)

#define COMPUTEG(BF, bufi)                                                     \
  do {                                                                         \
    _Pragma("unroll") for (int c = 0; c < 2; ++c) {                            \
      half8 af[4];                                                             \
      _Pragma("unroll") for (int t = 0; t < 4; ++t) af[t] =                    \
          *reinterpret_cast<const half8*>(                                     \
              &smem[(bufi)*4096 + ((t * 2 + c) * 64 + lane) * 8]);             \
      _Pragma("unroll") for (int t = 0; t < 4; ++t) acc[t] =                   \
          MFMA32(af[t], BF[c], acc[t]);                                        \
    }                                                                          \
  } while (0)

  STAGEA(0, 0);
  LOADB(bA, 0);
  __syncthreads();

#pragma unroll 1
  for (int it = 0; it < D / 64; it += 2) {
    STAGEA(1, (it + 1) * 64);
    LOADB(bB, (it + 1) * 64);
    COMPUTEG(bA, 0);
    __syncthreads();
    if (it + 2 < D / 64) {
      STAGEA(0, (it + 2) * 64);
      LOADB(bA, (it + 2) * 64);
    }
    COMPUTEG(bB, 1);
    __syncthreads();
  }
#undef STAGEA
#undef LOADB
#undef COMPUTEG

  float bv = bias[j0 + wc * 16 + lr];
#pragma unroll
  for (int t = 0; t < 4; ++t) {
#pragma unroll
    for (int r = 0; r < 4; ++r) {
      int gr = row0 + t * 16 + lq * 4 + r;
      int gc = j0 + wc * 16 + lr;
      Out[(size_t)gr * D + gc] = acc[t][r] + bv;
    }
  }
}

// ---------------------------------------------------------------------------
// Flash attention, in-block split-K. 512 threads (8 waves), 64 q-rows/block.
// Wave w: q-subtile t=w&3 (16 rows), k'-half = w>>2 (2 of 4 u-tiles/iter).
//   - K-fragments loaded global->registers (L2-resident), double-buffered,
//     loop unrolled x2 (no reg copies). Only V goes through LDS (24KB).
//   - S^T = K*Q^T: C-layout == A-frag layout of 16x16x16 -> P in registers.
//   - exp2 (v_exp_f32) with 0.125*log2e folded into Q scale.
//   - l via ones-MFMA. Partials additive; merged once at the end via LDS.
// ---------------------------------------------------------------------------
__global__ __launch_bounds__(512, 6) void attn_mfma_kernel(
    const half_t* __restrict__ Qh, const half_t* __restrict__ Kh,
    const half_t* __restrict__ Vt_g, half_t* __restrict__ Oh) {
  // Vs: 2 buffers x 8 groups x 512 halfs = 8192; reduction needs 10400.
  __shared__ __align__(16) half_t smem[12288];  // 24KB
  half_t* Vs = smem;

  const int tid = threadIdx.x;
  const int lane = tid & 63;
  const int wv = tid >> 6;       // 0..7
  const int t_ = wv & 3;         // q-subtile
  const int half_ = wv >> 2;     // k'-half
  const int lr = lane & 15;
  const int lq = lane >> 4;
  const int q0 = blockIdx.x * 64;
  const int h = blockIdx.y;
  const int b = blockIdx.z;
  const size_t base = (size_t)b * S * D + h * HD;              // + row*D
  const size_t vtbase = (size_t)(b * H + h) * HD * (size_t)S;  // + d*S + s
  const int qw = q0 + t_ * 16;

  // Q B-fragments, scale = (1/8)*log2(e) -> exp2 later
  const half_t qscale = (half_t)0.18033688f;
  half8 qf[2];
#pragma unroll
  for (int c = 0; c < 2; ++c) {
    half8 qv = *reinterpret_cast<const half8*>(
        &Qh[base + (size_t)(qw + lr) * D + c * 32 + lq * 8]);
#pragma unroll
    for (int j = 0; j < 8; ++j) qv[j] = qv[j] * qscale;
    qf[c] = qv;
  }

  half4 ones;
#pragma unroll
  for (int j = 0; j < 4; ++j) ones[j] = (half_t)1.0f;

  floatx4 o[4] = {};
  floatx4 ol = {};
  half8 kf0[2][2], kf1[2][2];  // [ui][c]

  // V staging: 8 groups, 1 per wave
#define STAGEV(bufi, kb)                                                       \
  do {                                                                         \
    int ud = wv >> 1, c = wv & 1;                                              \
    gl_lds16(                                                                  \
        Vt_g + vtbase + (size_t)(ud * 16 + lr) * S + (kb) + c * 32 + lq * 8,   \
        Vs + (bufi)*4096 + wv * 512);                                          \
  } while (0)

#define LOADK(KF, kb)                                                          \
  do {                                                                         \
    _Pragma("unroll") for (int ui = 0; ui < 2; ++ui)                           \
        _Pragma("unroll") for (int c = 0; c < 2; ++c) KF[ui][c] =              \
        *reinterpret_cast<const half8*>(                                       \
            &Kh[base + (size_t)((kb) + (half_ * 2 + ui) * 16 + lr) * D +       \
                c * 32 + lq * 8]);                                             \
  } while (0)

#define ACOMPUTE(KF, CUR)                                                      \
  do {                                                                         \
    _Pragma("unroll") for (int ui = 0; ui < 2; ++ui) {                         \
      const int u = half_ * 2 + ui;                                            \
      floatx4 st = {};                                                         \
      st = MFMA32(KF[ui][0], qf[0], st);                                       \
      st = MFMA32(KF[ui][1], qf[1], st);                                       \
      half4 pf;                                                                \
      pf[0] = (half_t)EXP2F(st[0]);                                            \
      pf[1] = (half_t)EXP2F(st[1]);                                            \
      pf[2] = (half_t)EXP2F(st[2]);                                            \
      pf[3] = (half_t)EXP2F(st[3]);                                            \
      _Pragma("unroll") for (int ud = 0; ud < 4; ++ud) {                       \
        half4 vf = *reinterpret_cast<const half4*>(                            \
            &Vs[(CUR)*4096 +                                                   \
                ((ud * 2 + (u >> 1)) * 64 +                                    \
                 ((((u & 1) * 2) + (lq >> 1)) * 16 + lr)) *                    \
                    8 +                                                        \
                (lq & 1) * 4]);                                                \
        o[ud] = MFMA16(pf, vf, o[ud]);                                         \
      }                                                                        \
      ol = MFMA16(pf, ones, ol);                                               \
    }                                                                          \
  } while (0)

  STAGEV(0, 0);
  LOADK(kf0, 0);
  __syncthreads();

#pragma unroll 1
  for (int it = 0; it < S / 64; it += 2) {
    STAGEV(1, (it + 1) * 64);
    LOADK(kf1, (it + 1) * 64);
    ACOMPUTE(kf0, 0);
    __syncthreads();
    if (it + 2 < S / 64) {
      STAGEV(0, (it + 2) * 64);
      LOADK(kf0, (it + 2) * 64);
    }
    ACOMPUTE(kf1, 1);
    __syncthreads();
  }
#undef STAGEV
#undef LOADK
#undef ACOMPUTE

  // merge k'-halves: waves 4-7 deposit partials (SoA, stride 260), 0-3 reduce
  float* red = (float*)smem;  // 20 comps x 260 floats = 20.8KB <= 24KB
  const int slot = t_ * 64 + lane;  // 0..255
  if (half_ == 1) {
#pragma unroll
    for (int comp = 0; comp < 16; ++comp)
      red[comp * 260 + slot] = o[comp >> 2][comp & 3];
#pragma unroll
    for (int r = 0; r < 4; ++r) red[(16 + r) * 260 + slot] = ol[r];
  }
  __syncthreads();
  if (half_ == 0) {
#pragma unroll
    for (int comp = 0; comp < 16; ++comp)
      o[comp >> 2][comp & 3] += red[comp * 260 + slot];
    float linv[4];
#pragma unroll
    for (int r = 0; r < 4; ++r)
      linv[r] = 1.0f / (ol[r] + red[(16 + r) * 260 + slot]);
#pragma unroll
    for (int ud = 0; ud < 4; ++ud) {
#pragma unroll
      for (int r = 0; r < 4; ++r) {
        int row = qw + lq * 4 + r;
        int col = h * HD + ud * 16 + lr;
        Oh[(size_t)(b * S + row) * D + col] = (half_t)(o[ud][r] * linv[r]);
      }
    }
  }
}

// ---------------------------------------------------------------------------
// Launch
// ---------------------------------------------------------------------------
extern "C" void kernel_launch(void* const* d_in, const int* in_sizes, int n_in,
                              void* d_out, int out_size, void* d_ws,
                              size_t ws_size, hipStream_t stream) {
  const float* query = (const float*)d_in[0];
  const float* key   = (const float*)d_in[1];
  const float* value = (const float*)d_in[2];
  const float* Wq = (const float*)d_in[3];
  const float* bq = (const float*)d_in[4];
  const float* Aq = (const float*)d_in[5];
  const float* Wk = (const float*)d_in[6];
  const float* bk = (const float*)d_in[7];
  const float* Ak = (const float*)d_in[8];
  const float* Wv = (const float*)d_in[9];
  const float* bv = (const float*)d_in[10];
  const float* Av = (const float*)d_in[11];
  const float* Wo = (const float*)d_in[12];
  const float* bo = (const float*)d_in[13];
  float* out = (float*)d_out;

  half_t* hw = (half_t*)d_ws;
  const size_t XSZ = (size_t)NROWS * D;  // 3145728
  const size_t MSZ = (size_t)D * D;      // 589824
  half_t* xq = hw;              // converted inputs (fp16)
  half_t* xk = xq + XSZ;
  half_t* xv = xk + XSZ;
  half_t* qh = xv + XSZ;        // Q projection [n][D]
  half_t* kh = qh + XSZ;        // K projection [n][D]
  half_t* vt = kh + XSZ;        // V projection TRANSPOSED [b][h][d][S]
  half_t* ab = vt + XSZ;        // attention output [n][D]
  half_t* Mq = ab + XSZ;
  half_t* Mk = Mq + MSZ;
  half_t* Mv = Mk + MSZ;
  half_t* Mo = Mv + MSZ;

  prep_kernel<<<18432, 256, 0, stream>>>(query, key, value, xq, xk, xv, Wq, Aq,
                                         Wk, Ak, Wv, Av, Wo, Mq, Mk, Mv, Mo);

  dim3 gq(D / 128, NROWS / 64, 3);  // (6, 64, 3) = 1152 blocks
  gemm_qkv_kernel<<<gq, 256, 0, stream>>>(xq, xk, xv, Mq, Mk, Mv, bq, bk, bv,
                                          qh, kh, vt);

  dim3 ga(S / 64, H, B_);  // (32, 12, 2)
  attn_mfma_kernel<<<ga, 512, 0, stream>>>(qh, kh, vt, ab);

  dim3 go(D / 64, NROWS / 64, 1);  // (12, 64) = 768 blocks
  gemm_o_kernel<<<go, 256, 0, stream>>>(ab, Mo, bo, out);
}

// Round 10
// 246.436 us; speedup vs baseline: 1.4187x; 1.4187x over previous
//
#include <hip/hip_runtime.h>
#include <math.h>
#include <stdint.h>

// Problem constants
#define D 768
#define S 2048
#define B_ 2
#define NROWS 4096   // B_*S
#define H 12
#define HD 64
#define R_ 16

typedef _Float16 half_t;
typedef _Float16 half8 __attribute__((ext_vector_type(8)));
typedef _Float16 half4 __attribute__((ext_vector_type(4)));
typedef float floatx4 __attribute__((ext_vector_type(4)));

#define MFMA32(a, b, c) __builtin_amdgcn_mfma_f32_16x16x32_f16(a, b, c, 0, 0, 0)
#define MFMA16(a, b, c) __builtin_amdgcn_mfma_f32_16x16x16f16(a, b, c, 0, 0, 0)
#define EXP2F(x) __builtin_amdgcn_exp2f(x)

// global -> LDS async DMA, 16B per lane; lane i lands at base + 16*i.
__device__ __forceinline__ void gl_lds16(const void* gp, half_t* lp) {
  __builtin_amdgcn_global_load_lds(
      (const __attribute__((address_space(1))) void*)(gp),
      (__attribute__((address_space(3))) void*)(lp), 16, 0, 0);
}

// ---------------------------------------------------------------------------
// Fused prep: blocks [0, 9216): fp32->fp16 convert of q,k,v.
//             blocks [9216, 18432): build folded LoRA weights
//             Mh[j][k] = W[j][k] + 4*sum_r A[k,r]A[j,r]  (fp16, [j][k]).
// ---------------------------------------------------------------------------
__global__ __launch_bounds__(256) void prep_kernel(
    const float* __restrict__ q, const float* __restrict__ k,
    const float* __restrict__ v, half_t* __restrict__ xq,
    half_t* __restrict__ xk, half_t* __restrict__ xv,
    const float* __restrict__ Wq, const float* __restrict__ Aq,
    const float* __restrict__ Wk, const float* __restrict__ Ak,
    const float* __restrict__ Wv, const float* __restrict__ Av,
    const float* __restrict__ Wo, half_t* __restrict__ Mq,
    half_t* __restrict__ Mk, half_t* __restrict__ Mv,
    half_t* __restrict__ Mo) {
  const int bid = blockIdx.x;
  if (bid < 9216) {
    const int y = bid / 3072;
    const float* x = (y == 0) ? q : (y == 1) ? k : v;
    half_t* o = (y == 0) ? xq : (y == 1) ? xk : xv;
    int i = (bid - y * 3072) * 1024 + threadIdx.x * 4;
    float4 vv = *reinterpret_cast<const float4*>(x + i);
    half_t tmp[4] = {(half_t)vv.x, (half_t)vv.y, (half_t)vv.z, (half_t)vv.w};
    *reinterpret_cast<uint64_t*>(o + i) = *reinterpret_cast<uint64_t*>(tmp);
  } else {
    const int u = bid - 9216;
    const int y = u / 2304;
    const float* W = (y == 0) ? Wq : (y == 1) ? Wk : (y == 2) ? Wv : Wo;
    const float* A = (y == 0) ? Aq : (y == 1) ? Ak : (y == 2) ? Av : nullptr;
    half_t* M = (y == 0) ? Mq : (y == 1) ? Mk : (y == 2) ? Mv : Mo;
    int idx = (u - y * 2304) * 256 + threadIdx.x;  // j*768 + k
    int j = idx / D;
    int kk = idx - j * D;
    float acc = W[idx];
    if (A != nullptr) {
      float s = 0.f;
#pragma unroll
      for (int r = 0; r < R_; ++r) s += A[kk * R_ + r] * A[j * R_ + r];
      acc += 4.0f * s;
    }
    M[idx] = (half_t)acc;
  }
}

// ---------------------------------------------------------------------------
// QKV GEMM (fp16 in/out): C[n][j] = sum_k X[n][k]*Mh[j][k] + bias[j].
// 128x128 tile, 4 waves (2x2). A: DMA->LDS double-buffered (32KB).
// B: global->registers double-buffered (M is L2-resident; 256-thread blocks
// leave VGPR headroom -- no launch_bounds cap, ~165 VGPR). 1 barrier/iter.
// z==2 writes V output TRANSPOSED per head (two 64-row passes through LDS).
// ---------------------------------------------------------------------------
__global__ __launch_bounds__(256) void gemm_qkv_kernel(
    const half_t* __restrict__ x0, const half_t* __restrict__ x1,
    const half_t* __restrict__ x2, const half_t* __restrict__ m0,
    const half_t* __restrict__ m1, const half_t* __restrict__ m2,
    const float* __restrict__ b0, const float* __restrict__ b1,
    const float* __restrict__ b2, half_t* __restrict__ o0,
    half_t* __restrict__ o1, half_t* __restrict__ o2) {
  constexpr int TRS = 72;  // V-transpose stride (halfs, %8==0)
  // A staging: 2 buffers x 16 groups x 512 halfs = 16384 halfs = 32KB.
  // V-transpose pass reuses it: 128 ch x 72 halfs = 9216 <= 16384. OK.
  __shared__ __align__(16) half_t smem[16384];

  const int z = blockIdx.z;
  const half_t* X = (z == 0) ? x0 : (z == 1) ? x1 : x2;
  const half_t* M = (z == 0) ? m0 : (z == 1) ? m1 : m2;
  const float* bias = (z == 0) ? b0 : (z == 1) ? b1 : b2;
  half_t* Out = (z == 0) ? o0 : (z == 1) ? o1 : o2;

  const int tid = threadIdx.x;
  const int lane = tid & 63;
  const int wv = tid >> 6;
  const int lr = lane & 15;
  const int lq = lane >> 4;
  const int row0 = blockIdx.y * 128;
  const int j0 = blockIdx.x * 128;
  const int wr = wv >> 1;  // wave row 0..1
  const int wc = wv & 1;   // wave col 0..1

  floatx4 acc[4][4] = {};
  half8 bA[4][2], bB[4][2];  // [u][c] register double-buffer for B

#define STAGEA(bufi, k0)                                                       \
  do {                                                                         \
    _Pragma("unroll") for (int gi = 0; gi < 4; ++gi) {                         \
      int g = wv * 4 + gi;                                                     \
      int t = g >> 1, c = g & 1;                                               \
      gl_lds16(X + (size_t)(row0 + t * 16 + lr) * D + (k0) + c * 32 + lq * 8,  \
               smem + (bufi)*8192 + g * 512);                                  \
    }                                                                          \
  } while (0)

#define LOADB(BF, k0)                                                          \
  do {                                                                         \
    _Pragma("unroll") for (int u = 0; u < 4; ++u)                              \
        _Pragma("unroll") for (int c = 0; c < 2; ++c) BF[u][c] =               \
        *reinterpret_cast<const half8*>(                                       \
            &M[(size_t)(j0 + (wc * 4 + u) * 16 + lr) * D + (k0) + c * 32 +     \
               lq * 8]);                                                       \
  } while (0)

#define COMPUTEG(BF, bufi)                                                     \
  do {                                                                         \
    _Pragma("unroll") for (int c = 0; c < 2; ++c) {                            \
      half8 af[4];                                                             \
      _Pragma("unroll") for (int t = 0; t < 4; ++t) af[t] =                    \
          *reinterpret_cast<const half8*>(                                     \
              &smem[(bufi)*8192 + (((wr * 4 + t) * 2 + c) * 64 + lane) * 8]);  \
      _Pragma("unroll") for (int t = 0; t < 4; ++t)                            \
          _Pragma("unroll") for (int u = 0; u < 4; ++u) acc[t][u] =            \
          MFMA32(af[t], BF[u][c], acc[t][u]);                                  \
    }                                                                          \
  } while (0)

  STAGEA(0, 0);
  LOADB(bA, 0);
  __syncthreads();

#pragma unroll 1
  for (int it = 0; it < D / 64; it += 2) {
    STAGEA(1, (it + 1) * 64);
    LOADB(bB, (it + 1) * 64);
    COMPUTEG(bA, 0);
    __syncthreads();
    if (it + 2 < D / 64) {
      STAGEA(0, (it + 2) * 64);
      LOADB(bA, (it + 2) * 64);
    }
    COMPUTEG(bB, 1);
    __syncthreads();
  }
#undef STAGEA
#undef LOADB
#undef COMPUTEG

  float bv[4];
#pragma unroll
  for (int u = 0; u < 4; ++u) bv[u] = bias[j0 + (wc * 4 + u) * 16 + lr];

  if (z == 2) {
    // transpose through LDS in two 64-row passes, emit V^T [b][h][d][S]
    const int bb = row0 >> 11;
#pragma unroll 1
    for (int pass = 0; pass < 2; ++pass) {
      if (wr == pass) {
#pragma unroll
        for (int t = 0; t < 4; ++t) {
#pragma unroll
          for (int u = 0; u < 4; ++u) {
            int c_local = (wc * 4 + u) * 16 + lr;  // 0..127
#pragma unroll
            for (int r = 0; r < 4; ++r) {
              int r_local = t * 16 + lq * 4 + r;   // 0..63 within pass
              smem[c_local * TRS + r_local] = (half_t)(acc[t][u][r] + bv[u]);
            }
          }
        }
      }
      __syncthreads();
      const int s_base = (row0 & 2047) + pass * 64;
#pragma unroll
      for (int itc = 0; itc < 4; ++itc) {
        int unit = itc * 256 + tid;     // 0..1023
        int c_local = unit >> 3;        // channel 0..127
        int chunk = unit & 7;           // token chunk 0..7
        half8 vv =
            *reinterpret_cast<const half8*>(&smem[c_local * TRS + chunk * 8]);
        int gc = j0 + c_local;
        int hh = gc >> 6, dd = gc & 63;
        *reinterpret_cast<half8*>(
            &Out[((size_t)(bb * H + hh) * HD + dd) * S + s_base + chunk * 8]) =
            vv;
      }
      __syncthreads();
    }
    return;
  }

#pragma unroll
  for (int t = 0; t < 4; ++t) {
#pragma unroll
    for (int u = 0; u < 4; ++u) {
#pragma unroll
      for (int r = 0; r < 4; ++r) {
        int gr = row0 + (wr * 4 + t) * 16 + lq * 4 + r;
        int gc = j0 + (wc * 4 + u) * 16 + lr;
        Out[(size_t)gr * D + gc] = (half_t)(acc[t][u][r] + bv[u]);
      }
    }
  }
}

// ---------------------------------------------------------------------------
// Out-projection GEMM (fp16 in, fp32 out): 64x64 tile, 4 waves (1x4, 16
// cols each). A: DMA->LDS dbuf; B: global->regs dbuf. grid 768 = 3/CU.
// ---------------------------------------------------------------------------
__global__ __launch_bounds__(256) void gemm_o_kernel(
    const half_t* __restrict__ Xh, const half_t* __restrict__ M,
    const float* __restrict__ bias, float* __restrict__ Out) {
  __shared__ __align__(16) half_t smem[8192];  // 16KB: 2 x 8 A-groups

  const int tid = threadIdx.x;
  const int lane = tid & 63;
  const int wv = tid >> 6;
  const int lr = lane & 15;
  const int lq = lane >> 4;
  const int row0 = blockIdx.y * 64;
  const int j0 = blockIdx.x * 64;
  const int wc = wv;  // 16 cols per wave

  floatx4 acc[4] = {};
  half8 bA[2], bB[2];  // [c]

#define STAGEA(bufi, k0)                                                       \
  do {                                                                         \
    _Pragma("unroll") for (int gi = 0; gi < 2; ++gi) {                         \
      int g = wv * 2 + gi;                                                     \
      int t = g >> 1, c = g & 1;                                               \
      gl_lds16(Xh + (size_t)(row0 + t * 16 + lr) * D + (k0) + c * 32 + lq * 8, \
               smem + (bufi)*4096 + g * 512);                                  \
    }                                                                          \
  } while (0)

#define LOADB(BF, k0)                                                          \
  do {                                                                         \
    _Pragma("unroll") for (int c = 0; c < 2; ++c) BF[c] =                      \
        *reinterpret_cast<const half8*>(                                       \
            &M[(size_t)(j0 + wc * 16 + lr) * D + (k0) + c * 32 + lq * 8]);     \
  } while (0)

#define COMPUTEG(BF, bufi)                                                     \
  do {                                                                         \
    _Pragma("unroll") for (int c = 0; c < 2; ++c) {                            \
      half8 af[4];                                                             \
      _Pragma("unroll") for (int t = 0; t < 4; ++t) af[t] =                    \
          *reinterpret_cast<const half8*>(                                     \
              &smem[(bufi)*4096 + ((t * 2 + c) * 64 + lane) * 8]);             \
      _Pragma("unroll") for (int t = 0; t < 4; ++t) acc[t] =                   \
          MFMA32(af[t], BF[c], acc[t]);                                        \
    }                                                                          \
  } while (0)

  STAGEA(0, 0);
  LOADB(bA, 0);
  __syncthreads();

#pragma unroll 1
  for (int it = 0; it < D / 64; it += 2) {
    STAGEA(1, (it + 1) * 64);
    LOADB(bB, (it + 1) * 64);
    COMPUTEG(bA, 0);
    __syncthreads();
    if (it + 2 < D / 64) {
      STAGEA(0, (it + 2) * 64);
      LOADB(bA, (it + 2) * 64);
    }
    COMPUTEG(bB, 1);
    __syncthreads();
  }
#undef STAGEA
#undef LOADB
#undef COMPUTEG

  float bv = bias[j0 + wc * 16 + lr];
#pragma unroll
  for (int t = 0; t < 4; ++t) {
#pragma unroll
    for (int r = 0; r < 4; ++r) {
      int gr = row0 + t * 16 + lq * 4 + r;
      int gc = j0 + wc * 16 + lr;
      Out[(size_t)gr * D + gc] = acc[t][r] + bv;
    }
  }
}

// ---------------------------------------------------------------------------
// Flash attention, in-block split-K (r8-exact: K and V both LDS-staged; 36
// VGPR, no spills). 512 threads (8 waves), 64 q-rows/block.
// Wave w: q-subtile t=w&3 (16 rows), k'-half = w>>2 (2 of 4 u-tiles/iter).
// Partials are additive (no running max) -> merged once at the end via LDS.
//   - S^T = K*Q^T: C-layout == A-frag layout of 16x16x16 -> P in registers.
//   - exp2 (v_exp_f32) with 0.125*log2e folded into Q scale.
//   - l via ones-MFMA: ol[r] = row-sum of P, reg-aligned with o.
// ---------------------------------------------------------------------------
__global__ __launch_bounds__(512, 6) void attn_mfma_kernel(
    const half_t* __restrict__ Qh, const half_t* __restrict__ Kh,
    const half_t* __restrict__ Vt_g, half_t* __restrict__ Oh) {
  __shared__ __align__(16) half_t smem[16384];  // 32KB: Ks[2][4k] Vs[2][4k]
  half_t* Ks = smem;           // [2][8*512]
  half_t* Vs = smem + 8192;    // [2][8*512]

  const int tid = threadIdx.x;
  const int lane = tid & 63;
  const int wv = tid >> 6;       // 0..7
  const int t_ = wv & 3;         // q-subtile
  const int half_ = wv >> 2;     // k'-half
  const int lr = lane & 15;
  const int lq = lane >> 4;
  const int q0 = blockIdx.x * 64;
  const int h = blockIdx.y;
  const int b = blockIdx.z;
  const size_t base = (size_t)b * S * D + h * HD;              // + row*D
  const size_t vtbase = (size_t)(b * H + h) * HD * (size_t)S;  // + d*S + s
  const int qw = q0 + t_ * 16;

  // Q B-fragments, scale = (1/8)*log2(e) -> exp2 later
  const half_t qscale = (half_t)0.18033688f;
  half8 qf[2];
#pragma unroll
  for (int c = 0; c < 2; ++c) {
    half8 qv = *reinterpret_cast<const half8*>(
        &Qh[base + (size_t)(qw + lr) * D + c * 32 + lq * 8]);
#pragma unroll
    for (int j = 0; j < 8; ++j) qv[j] = qv[j] * qscale;
    qf[c] = qv;
  }

  half4 ones;
#pragma unroll
  for (int j = 0; j < 4; ++j) ones[j] = (half_t)1.0f;

  floatx4 o[4] = {};
  floatx4 ol = {};

  // 16 DMA groups (8 K + 8 V), 2 per wave
#define STAGE(bufi, kb)                                                        \
  do {                                                                         \
    _Pragma("unroll") for (int gi = 0; gi < 2; ++gi) {                         \
      int g = wv * 2 + gi;                                                     \
      if (g < 8) {                                                             \
        int u = g >> 1, c = g & 1;                                             \
        gl_lds16(                                                              \
            Kh + base + (size_t)((kb) + u * 16 + lr) * D + c * 32 + lq * 8,    \
            Ks + (bufi)*4096 + g * 512);                                       \
      } else {                                                                 \
        int gv = g - 8;                                                        \
        int ud = gv >> 1, c = gv & 1;                                          \
        gl_lds16(                                                              \
            Vt_g + vtbase + (size_t)(ud * 16 + lr) * S + (kb) + c * 32 +       \
                lq * 8,                                                        \
            Vs + (bufi)*4096 + gv * 512);                                      \
      }                                                                        \
    }                                                                          \
  } while (0)

  STAGE(0, 0);
  __syncthreads();

  for (int it = 0; it < S / 64; ++it) {
    const int cur = it & 1;
    if (it + 1 < S / 64) STAGE(cur ^ 1, (it + 1) * 64);

#pragma unroll
    for (int ui = 0; ui < 2; ++ui) {
      const int u = half_ * 2 + ui;
      half8 kf0 = *reinterpret_cast<const half8*>(
          &Ks[cur * 4096 + ((u * 2 + 0) * 64 + lane) * 8]);
      half8 kf1 = *reinterpret_cast<const half8*>(
          &Ks[cur * 4096 + ((u * 2 + 1) * 64 + lane) * 8]);
      floatx4 st = {};
      st = MFMA32(kf0, qf[0], st);
      st = MFMA32(kf1, qf[1], st);
      half4 pf;
      pf[0] = (half_t)EXP2F(st[0]);
      pf[1] = (half_t)EXP2F(st[1]);
      pf[2] = (half_t)EXP2F(st[2]);
      pf[3] = (half_t)EXP2F(st[3]);
#pragma unroll
      for (int ud = 0; ud < 4; ++ud) {
        half4 vf = *reinterpret_cast<const half4*>(
            &Vs[cur * 4096 + ((ud * 2 + (u >> 1)) * 64 +
                              ((((u & 1) * 2) + (lq >> 1)) * 16 + lr)) *
                                 8 +
                (lq & 1) * 4]);
        o[ud] = MFMA16(pf, vf, o[ud]);
      }
      ol = MFMA16(pf, ones, ol);  // row-sums -> l, reg-aligned with o
    }
    __syncthreads();
  }
#undef STAGE

  // merge k'-halves: waves 4-7 deposit partials (SoA, stride 260), 0-3 reduce
  float* red = (float*)smem;  // 20 comps x 260 floats = 20.8KB <= 32KB
  const int slot = t_ * 64 + lane;  // 0..255
  if (half_ == 1) {
#pragma unroll
    for (int comp = 0; comp < 16; ++comp)
      red[comp * 260 + slot] = o[comp >> 2][comp & 3];
#pragma unroll
    for (int r = 0; r < 4; ++r) red[(16 + r) * 260 + slot] = ol[r];
  }
  __syncthreads();
  if (half_ == 0) {
#pragma unroll
    for (int comp = 0; comp < 16; ++comp)
      o[comp >> 2][comp & 3] += red[comp * 260 + slot];
    float linv[4];
#pragma unroll
    for (int r = 0; r < 4; ++r)
      linv[r] = 1.0f / (ol[r] + red[(16 + r) * 260 + slot]);
#pragma unroll
    for (int ud = 0; ud < 4; ++ud) {
#pragma unroll
      for (int r = 0; r < 4; ++r) {
        int row = qw + lq * 4 + r;
        int col = h * HD + ud * 16 + lr;
        Oh[(size_t)(b * S + row) * D + col] = (half_t)(o[ud][r] * linv[r]);
      }
    }
  }
}

// ---------------------------------------------------------------------------
// Launch
// ---------------------------------------------------------------------------
extern "C" void kernel_launch(void* const* d_in, const int* in_sizes, int n_in,
                              void* d_out, int out_size, void* d_ws,
                              size_t ws_size, hipStream_t stream) {
  const float* query = (const float*)d_in[0];
  const float* key   = (const float*)d_in[1];
  const float* value = (const float*)d_in[2];
  const float* Wq = (const float*)d_in[3];
  const float* bq = (const float*)d_in[4];
  const float* Aq = (const float*)d_in[5];
  const float* Wk = (const float*)d_in[6];
  const float* bk = (const float*)d_in[7];
  const float* Ak = (const float*)d_in[8];
  const float* Wv = (const float*)d_in[9];
  const float* bv = (const float*)d_in[10];
  const float* Av = (const float*)d_in[11];
  const float* Wo = (const float*)d_in[12];
  const float* bo = (const float*)d_in[13];
  float* out = (float*)d_out;

  half_t* hw = (half_t*)d_ws;
  const size_t XSZ = (size_t)NROWS * D;  // 3145728
  const size_t MSZ = (size_t)D * D;      // 589824
  half_t* xq = hw;              // converted inputs (fp16)
  half_t* xk = xq + XSZ;
  half_t* xv = xk + XSZ;
  half_t* qh = xv + XSZ;        // Q projection [n][D]
  half_t* kh = qh + XSZ;        // K projection [n][D]
  half_t* vt = kh + XSZ;        // V projection TRANSPOSED [b][h][d][S]
  half_t* ab = vt + XSZ;        // attention output [n][D]
  half_t* Mq = ab + XSZ;
  half_t* Mk = Mq + MSZ;
  half_t* Mv = Mk + MSZ;
  half_t* Mo = Mv + MSZ;

  prep_kernel<<<18432, 256, 0, stream>>>(query, key, value, xq, xk, xv, Wq, Aq,
                                         Wk, Ak, Wv, Av, Wo, Mq, Mk, Mv, Mo);

  dim3 gq(D / 128, NROWS / 128, 3);  // (6, 32, 3) = 576 blocks
  gemm_qkv_kernel<<<gq, 256, 0, stream>>>(xq, xk, xv, Mq, Mk, Mv, bq, bk, bv,
                                          qh, kh, vt);

  dim3 ga(S / 64, H, B_);  // (32, 12, 2)
  attn_mfma_kernel<<<ga, 512, 0, stream>>>(qh, kh, vt, ab);

  dim3 go(D / 64, NROWS / 64, 1);  // (12, 64) = 768 blocks
  gemm_o_kernel<<<go, 256, 0, stream>>>(ab, Mo, bo, out);
}

// Round 11
// 223.068 us; speedup vs baseline: 1.5673x; 1.1048x over previous
//
#include <hip/hip_runtime.h>
#include <math.h>
#include <stdint.h>

// Problem constants
#define D 768
#define S 2048
#define B_ 2
#define NROWS 4096   // B_*S
#define H 12
#define HD 64
#define R_ 16

typedef _Float16 half_t;
typedef _Float16 half8 __attribute__((ext_vector_type(8)));
typedef _Float16 half4 __attribute__((ext_vector_type(4)));
typedef float floatx4 __attribute__((ext_vector_type(4)));

#define MFMA32(a, b, c) __builtin_amdgcn_mfma_f32_16x16x32_f16(a, b, c, 0, 0, 0)
#define MFMA16(a, b, c) __builtin_amdgcn_mfma_f32_16x16x16f16(a, b, c, 0, 0, 0)
#define EXP2F(x) __builtin_amdgcn_exp2f(x)

// global -> LDS async DMA, 16B per lane; lane i lands at base + 16*i.
__device__ __forceinline__ void gl_lds16(const void* gp, half_t* lp) {
  __builtin_amdgcn_global_load_lds(
      (const __attribute__((address_space(1))) void*)(gp),
      (__attribute__((address_space(3))) void*)(lp), 16, 0, 0);
}

// V^T tiled-fragment layout ("vt2"): per head bh = b*H+h, per 64-token block
// kb (32 blocks): 4096 halfs = groups (ud 0..3, h2 0..1) x 512 halfs; lane
// (lq,lr) holds 8 halfs: V[kb*64+32*h2+lq*4+{0..3}][ud*16+lr] ++
//                        V[kb*64+32*h2+16+lq*4+{0..3}][ud*16+lr].
// This is simultaneously (a) writable as coalesced half4 stores straight from
// the QKV GEMM accumulators, (b) DMA-copyable 1:1 into LDS, (c) readable as
// conflict-free ds_read_b128 giving both u-subtile B-fragments per lane.

// ---------------------------------------------------------------------------
// Fused prep: blocks [0, 9216): fp32->fp16 convert of q,k,v.
//             blocks [9216, 18432): build folded LoRA weights
//             Mh[j][k] = W[j][k] + 4*sum_r A[k,r]A[j,r]  (fp16, [j][k]).
// ---------------------------------------------------------------------------
__global__ __launch_bounds__(256) void prep_kernel(
    const float* __restrict__ q, const float* __restrict__ k,
    const float* __restrict__ v, half_t* __restrict__ xq,
    half_t* __restrict__ xk, half_t* __restrict__ xv,
    const float* __restrict__ Wq, const float* __restrict__ Aq,
    const float* __restrict__ Wk, const float* __restrict__ Ak,
    const float* __restrict__ Wv, const float* __restrict__ Av,
    const float* __restrict__ Wo, half_t* __restrict__ Mq,
    half_t* __restrict__ Mk, half_t* __restrict__ Mv,
    half_t* __restrict__ Mo) {
  const int bid = blockIdx.x;
  if (bid < 9216) {
    const int y = bid / 3072;
    const float* x = (y == 0) ? q : (y == 1) ? k : v;
    half_t* o = (y == 0) ? xq : (y == 1) ? xk : xv;
    int i = (bid - y * 3072) * 1024 + threadIdx.x * 4;
    float4 vv = *reinterpret_cast<const float4*>(x + i);
    half_t tmp[4] = {(half_t)vv.x, (half_t)vv.y, (half_t)vv.z, (half_t)vv.w};
    *reinterpret_cast<uint64_t*>(o + i) = *reinterpret_cast<uint64_t*>(tmp);
  } else {
    const int u = bid - 9216;
    const int y = u / 2304;
    const float* W = (y == 0) ? Wq : (y == 1) ? Wk : (y == 2) ? Wv : Wo;
    const float* A = (y == 0) ? Aq : (y == 1) ? Ak : (y == 2) ? Av : nullptr;
    half_t* M = (y == 0) ? Mq : (y == 1) ? Mk : (y == 2) ? Mv : Mo;
    int idx = (u - y * 2304) * 256 + threadIdx.x;  // j*768 + k
    int j = idx / D;
    int kk = idx - j * D;
    float acc = W[idx];
    if (A != nullptr) {
      float s = 0.f;
#pragma unroll
      for (int r = 0; r < R_; ++r) s += A[kk * R_ + r] * A[j * R_ + r];
      acc += 4.0f * s;
    }
    M[idx] = (half_t)acc;
  }
}

// ---------------------------------------------------------------------------
// QKV GEMM (fp16 in/out): C[n][j] = sum_k X[n][k]*Mh[j][k] + bias[j].
// 64x128 tile, 4 waves (1x4), BK=64, both operands DMA-prefetched,
// double-buffered, one barrier per iter. 48KB LDS. (r8-proven structure)
// z==2 writes V output in vt2 layout via direct coalesced half4 stores.
// ---------------------------------------------------------------------------
__global__ __launch_bounds__(256) void gemm_qkv_kernel(
    const half_t* __restrict__ x0, const half_t* __restrict__ x1,
    const half_t* __restrict__ x2, const half_t* __restrict__ m0,
    const half_t* __restrict__ m1, const half_t* __restrict__ m2,
    const float* __restrict__ b0, const float* __restrict__ b1,
    const float* __restrict__ b2, half_t* __restrict__ o0,
    half_t* __restrict__ o1, half_t* __restrict__ o2) {
  constexpr int AG = 8;        // A groups (64 rows x 64 k)
  constexpr int G = AG + 16;   // + B groups (128 cols x 64 k)
  constexpr int PB = G * 512;  // 12288 halfs = 24KB per buffer
  __shared__ __align__(16) half_t smem[2 * PB];  // 48KB

  const int z = blockIdx.z;
  const half_t* X = (z == 0) ? x0 : (z == 1) ? x1 : x2;
  const half_t* M = (z == 0) ? m0 : (z == 1) ? m1 : m2;
  const float* bias = (z == 0) ? b0 : (z == 1) ? b1 : b2;
  half_t* Out = (z == 0) ? o0 : (z == 1) ? o1 : o2;

  const int tid = threadIdx.x;
  const int lane = tid & 63;
  const int wv = tid >> 6;
  const int lr = lane & 15;
  const int lq = lane >> 4;
  const int row0 = blockIdx.y * 64;
  const int j0 = blockIdx.x * 128;
  const int wc = wv;  // 1x4 wave grid, 32 cols per wave

  floatx4 acc[4][2] = {};

#define GSTAGE(bufi, k0)                                                       \
  do {                                                                         \
    _Pragma("unroll") for (int gi = 0; gi < 6; ++gi) {                         \
      int g = wv * 6 + gi;                                                     \
      if (g < AG) {                                                            \
        int t = g >> 1, c = g & 1;                                             \
        gl_lds16(                                                              \
            X + (size_t)(row0 + t * 16 + lr) * D + (k0) + c * 32 + lq * 8,     \
            smem + (bufi)*PB + g * 512);                                       \
      } else {                                                                 \
        int g2 = g - AG;                                                       \
        int u = g2 >> 1, c = g2 & 1;                                           \
        gl_lds16(                                                              \
            M + (size_t)(j0 + u * 16 + lr) * D + (k0) + c * 32 + lq * 8,       \
            smem + (bufi)*PB + AG * 512 + g2 * 512);                           \
      }                                                                        \
    }                                                                          \
  } while (0)

  GSTAGE(0, 0);
  __syncthreads();

  for (int it = 0; it < D / 64; ++it) {
    const int cur = it & 1;
    if (it + 1 < D / 64) GSTAGE(cur ^ 1, (it + 1) * 64);
    const half_t* Ab = smem + cur * PB;
    const half_t* Bb = Ab + AG * 512;
#pragma unroll
    for (int c = 0; c < 2; ++c) {
      half8 af[4], bf[2];
#pragma unroll
      for (int t = 0; t < 4; ++t)
        af[t] = *reinterpret_cast<const half8*>(
            &Ab[((t * 2 + c) * 64 + lane) * 8]);
#pragma unroll
      for (int u = 0; u < 2; ++u)
        bf[u] = *reinterpret_cast<const half8*>(
            &Bb[(((wc * 2 + u) * 2 + c) * 64 + lane) * 8]);
#pragma unroll
      for (int t = 0; t < 4; ++t)
#pragma unroll
        for (int u = 0; u < 2; ++u) acc[t][u] = MFMA32(af[t], bf[u], acc[t][u]);
    }
    __syncthreads();
  }
#undef GSTAGE

  float bv[2];
#pragma unroll
  for (int u = 0; u < 2; ++u) bv[u] = bias[j0 + (wc * 2 + u) * 16 + lr];

  if (z == 2) {
    // Direct vt2 stores from registers: for (t,u) the 4 r-values are one
    // contiguous half4 at group (ud = (wc*2+u)&3, h2 = t>>1), lane slot.
    const int bb = row0 >> 11;
    const int kb = (row0 & 2047) >> 6;
#pragma unroll
    for (int t = 0; t < 4; ++t) {
#pragma unroll
      for (int u = 0; u < 2; ++u) {
        int gc = j0 + (wc * 2 + u) * 16 + lr;
        int hh = gc >> 6;
        int ud = (wc * 2 + u) & 3;
        half4 hv;
#pragma unroll
        for (int r = 0; r < 4; ++r) hv[r] = (half_t)(acc[t][u][r] + bv[u]);
        size_t addr = ((size_t)(bb * H + hh) * HD) * S + (size_t)kb * 4096 +
                      (ud * 2 + (t >> 1)) * 512 + lane * 8 + (t & 1) * 4;
        *reinterpret_cast<half4*>(&Out[addr]) = hv;
      }
    }
    return;
  }

#pragma unroll
  for (int t = 0; t < 4; ++t) {
#pragma unroll
    for (int u = 0; u < 2; ++u) {
#pragma unroll
      for (int r = 0; r < 4; ++r) {
        int gr = row0 + t * 16 + lq * 4 + r;
        int gc = j0 + (wc * 2 + u) * 16 + lr;
        Out[(size_t)gr * D + gc] = (half_t)(acc[t][u][r] + bv[u]);
      }
    }
  }
}

// ---------------------------------------------------------------------------
// Out-projection GEMM (fp16 in, fp32 out): 64x64 tile, 4 waves (2x2 -> 32
// rows x 32 cols each; 8 b128-reads : 8 MFMA per wave-iter). All-DMA
// double-buffered, one barrier per iter. 32KB LDS, grid 768 = 3 blocks/CU.
// ---------------------------------------------------------------------------
__global__ __launch_bounds__(256) void gemm_o_kernel(
    const half_t* __restrict__ Xh, const half_t* __restrict__ M,
    const float* __restrict__ bias, float* __restrict__ Out) {
  constexpr int AG = 8;        // A groups (64 rows)
  constexpr int G = 16;        // + 8 B groups (64 cols)
  constexpr int PB = G * 512;  // 8192 halfs = 16KB per buffer
  __shared__ __align__(16) half_t smem[2 * PB];  // 32KB

  const int tid = threadIdx.x;
  const int lane = tid & 63;
  const int wv = tid >> 6;
  const int lr = lane & 15;
  const int lq = lane >> 4;
  const int row0 = blockIdx.y * 64;
  const int j0 = blockIdx.x * 64;
  const int wr = wv >> 1;  // wave row 0..1
  const int wc = wv & 1;   // wave col 0..1

  floatx4 acc[2][2] = {};

#define GSTAGE(bufi, k0)                                                       \
  do {                                                                         \
    _Pragma("unroll") for (int gi = 0; gi < 4; ++gi) {                         \
      int g = wv * 4 + gi;                                                     \
      if (g < AG) {                                                            \
        int t = g >> 1, c = g & 1;                                             \
        gl_lds16(                                                              \
            Xh + (size_t)(row0 + t * 16 + lr) * D + (k0) + c * 32 + lq * 8,    \
            smem + (bufi)*PB + g * 512);                                       \
      } else {                                                                 \
        int g2 = g - AG;                                                       \
        int u = g2 >> 1, c = g2 & 1;                                           \
        gl_lds16(                                                              \
            M + (size_t)(j0 + u * 16 + lr) * D + (k0) + c * 32 + lq * 8,       \
            smem + (bufi)*PB + AG * 512 + g2 * 512);                           \
      }                                                                        \
    }                                                                          \
  } while (0)

  GSTAGE(0, 0);
  __syncthreads();

  for (int it = 0; it < D / 64; ++it) {
    const int cur = it & 1;
    if (it + 1 < D / 64) GSTAGE(cur ^ 1, (it + 1) * 64);
    const half_t* Ab = smem + cur * PB;
    const half_t* Bb = Ab + AG * 512;
#pragma unroll
    for (int c = 0; c < 2; ++c) {
      half8 af[2], bf[2];
#pragma unroll
      for (int t = 0; t < 2; ++t)
        af[t] = *reinterpret_cast<const half8*>(
            &Ab[(((wr * 2 + t) * 2 + c) * 64 + lane) * 8]);
#pragma unroll
      for (int u = 0; u < 2; ++u)
        bf[u] = *reinterpret_cast<const half8*>(
            &Bb[(((wc * 2 + u) * 2 + c) * 64 + lane) * 8]);
#pragma unroll
      for (int t = 0; t < 2; ++t)
#pragma unroll
        for (int u = 0; u < 2; ++u) acc[t][u] = MFMA32(af[t], bf[u], acc[t][u]);
    }
    __syncthreads();
  }
#undef GSTAGE

  float bv[2];
#pragma unroll
  for (int u = 0; u < 2; ++u) bv[u] = bias[j0 + (wc * 2 + u) * 16 + lr];
#pragma unroll
  for (int t = 0; t < 2; ++t) {
#pragma unroll
    for (int u = 0; u < 2; ++u) {
#pragma unroll
      for (int r = 0; r < 4; ++r) {
        int gr = row0 + (wr * 2 + t) * 16 + lq * 4 + r;
        int gc = j0 + (wc * 2 + u) * 16 + lr;
        Out[(size_t)gr * D + gc] = acc[t][u][r] + bv[u];
      }
    }
  }
}

// ---------------------------------------------------------------------------
// Flash attention, in-block split-K. 512 threads (8 waves), 64 q-rows/block.
// Wave w: q-subtile t=w&3 (16 rows), k'-half = w>>2 (2 of 4 u-tiles/iter).
// K LDS-staged in B-frag order; V LDS-staged in vt2 interleaved layout so
// each PV step reads ONE ds_read_b128 per ud (both u-subtile fragments).
// Partials additive (no running max); merged once at the end via LDS.
//   - S^T = K*Q^T: C-layout == A-frag layout of 16x16x16 -> P in registers.
//   - exp2 (v_exp_f32) with 0.125*log2e folded into Q scale.
//   - l via ones-MFMA: ol[r] = row-sum of P, reg-aligned with o.
// ---------------------------------------------------------------------------
__global__ __launch_bounds__(512, 6) void attn_mfma_kernel(
    const half_t* __restrict__ Qh, const half_t* __restrict__ Kh,
    const half_t* __restrict__ Vt2, half_t* __restrict__ Oh) {
  __shared__ __align__(16) half_t smem[16384];  // 32KB: Ks[2][4k] Vs[2][4k]
  half_t* Ks = smem;           // [2][8*512]
  half_t* Vs = smem + 8192;    // [2][8*512]

  const int tid = threadIdx.x;
  const int lane = tid & 63;
  const int wv = tid >> 6;       // 0..7
  const int t_ = wv & 3;         // q-subtile
  const int half_ = wv >> 2;     // k'-half
  const int lr = lane & 15;
  const int lq = lane >> 4;
  const int q0 = blockIdx.x * 64;
  const int h = blockIdx.y;
  const int b = blockIdx.z;
  const size_t base = (size_t)b * S * D + h * HD;              // + row*D
  const size_t vtbase = (size_t)(b * H + h) * HD * (size_t)S;  // vt2 head base
  const int qw = q0 + t_ * 16;

  // Q B-fragments, scale = (1/8)*log2(e) -> exp2 later
  const half_t qscale = (half_t)0.18033688f;
  half8 qf[2];
#pragma unroll
  for (int c = 0; c < 2; ++c) {
    half8 qv = *reinterpret_cast<const half8*>(
        &Qh[base + (size_t)(qw + lr) * D + c * 32 + lq * 8]);
#pragma unroll
    for (int j = 0; j < 8; ++j) qv[j] = qv[j] * qscale;
    qf[c] = qv;
  }

  half4 ones;
#pragma unroll
  for (int j = 0; j < 4; ++j) ones[j] = (half_t)1.0f;

  floatx4 o[4] = {};
  floatx4 ol = {};

  // 16 DMA groups (8 K + 8 V), 2 per wave. V source is the LDS image itself.
#define STAGE(bufi, kb)                                                        \
  do {                                                                         \
    _Pragma("unroll") for (int gi = 0; gi < 2; ++gi) {                         \
      int g = wv * 2 + gi;                                                     \
      if (g < 8) {                                                             \
        int u = g >> 1, c = g & 1;                                             \
        gl_lds16(                                                              \
            Kh + base + (size_t)((kb) + u * 16 + lr) * D + c * 32 + lq * 8,    \
            Ks + (bufi)*4096 + g * 512);                                       \
      } else {                                                                 \
        int gv = g - 8;                                                        \
        gl_lds16(Vt2 + vtbase + (size_t)(kb)*64 + gv * 512 + lane * 8,         \
                 Vs + (bufi)*4096 + gv * 512);                                 \
      }                                                                        \
    }                                                                          \
  } while (0)

  STAGE(0, 0);
  __syncthreads();

  for (int it = 0; it < S / 64; ++it) {
    const int cur = it & 1;
    if (it + 1 < S / 64) STAGE(cur ^ 1, (it + 1) * 64);

    // S^T for both u-subtiles of this wave's k'-half
    half4 pf[2];
#pragma unroll
    for (int ui = 0; ui < 2; ++ui) {
      const int u = half_ * 2 + ui;
      half8 kf0 = *reinterpret_cast<const half8*>(
          &Ks[cur * 4096 + ((u * 2 + 0) * 64 + lane) * 8]);
      half8 kf1 = *reinterpret_cast<const half8*>(
          &Ks[cur * 4096 + ((u * 2 + 1) * 64 + lane) * 8]);
      floatx4 st = {};
      st = MFMA32(kf0, qf[0], st);
      st = MFMA32(kf1, qf[1], st);
      pf[ui][0] = (half_t)EXP2F(st[0]);
      pf[ui][1] = (half_t)EXP2F(st[1]);
      pf[ui][2] = (half_t)EXP2F(st[2]);
      pf[ui][3] = (half_t)EXP2F(st[3]);
    }
    // PV: one b128 per ud supplies both u-subtile B-fragments
#pragma unroll
    for (int ud = 0; ud < 4; ++ud) {
      half8 vf8 = *reinterpret_cast<const half8*>(
          &Vs[cur * 4096 + ((ud * 2 + half_) * 64 + lane) * 8]);
      half4 vlo, vhi;
#pragma unroll
      for (int j = 0; j < 4; ++j) {
        vlo[j] = vf8[j];
        vhi[j] = vf8[4 + j];
      }
      o[ud] = MFMA16(pf[0], vlo, o[ud]);
      o[ud] = MFMA16(pf[1], vhi, o[ud]);
    }
    ol = MFMA16(pf[0], ones, ol);
    ol = MFMA16(pf[1], ones, ol);
    __syncthreads();
  }
#undef STAGE

  // merge k'-halves: waves 4-7 deposit partials (SoA, stride 260), 0-3 reduce
  float* red = (float*)smem;  // 20 comps x 260 floats = 20.8KB <= 32KB
  const int slot = t_ * 64 + lane;  // 0..255
  if (half_ == 1) {
#pragma unroll
    for (int comp = 0; comp < 16; ++comp)
      red[comp * 260 + slot] = o[comp >> 2][comp & 3];
#pragma unroll
    for (int r = 0; r < 4; ++r) red[(16 + r) * 260 + slot] = ol[r];
  }
  __syncthreads();
  if (half_ == 0) {
#pragma unroll
    for (int comp = 0; comp < 16; ++comp)
      o[comp >> 2][comp & 3] += red[comp * 260 + slot];
    float linv[4];
#pragma unroll
    for (int r = 0; r < 4; ++r)
      linv[r] = 1.0f / (ol[r] + red[(16 + r) * 260 + slot]);
#pragma unroll
    for (int ud = 0; ud < 4; ++ud) {
#pragma unroll
      for (int r = 0; r < 4; ++r) {
        int row = qw + lq * 4 + r;
        int col = h * HD + ud * 16 + lr;
        Oh[(size_t)(b * S + row) * D + col] = (half_t)(o[ud][r] * linv[r]);
      }
    }
  }
}

// ---------------------------------------------------------------------------
// Launch
// ---------------------------------------------------------------------------
extern "C" void kernel_launch(void* const* d_in, const int* in_sizes, int n_in,
                              void* d_out, int out_size, void* d_ws,
                              size_t ws_size, hipStream_t stream) {
  const float* query = (const float*)d_in[0];
  const float* key   = (const float*)d_in[1];
  const float* value = (const float*)d_in[2];
  const float* Wq = (const float*)d_in[3];
  const float* bq = (const float*)d_in[4];
  const float* Aq = (const float*)d_in[5];
  const float* Wk = (const float*)d_in[6];
  const float* bk = (const float*)d_in[7];
  const float* Ak = (const float*)d_in[8];
  const float* Wv = (const float*)d_in[9];
  const float* bv = (const float*)d_in[10];
  const float* Av = (const float*)d_in[11];
  const float* Wo = (const float*)d_in[12];
  const float* bo = (const float*)d_in[13];
  float* out = (float*)d_out;

  half_t* hw = (half_t*)d_ws;
  const size_t XSZ = (size_t)NROWS * D;  // 3145728
  const size_t MSZ = (size_t)D * D;      // 589824
  half_t* xq = hw;              // converted inputs (fp16)
  half_t* xk = xq + XSZ;
  half_t* xv = xk + XSZ;
  half_t* qh = xv + XSZ;        // Q projection [n][D]
  half_t* kh = qh + XSZ;        // K projection [n][D]
  half_t* vt = kh + XSZ;        // V projection, vt2 tiled-fragment layout
  half_t* ab = vt + XSZ;        // attention output [n][D]
  half_t* Mq = ab + XSZ;
  half_t* Mk = Mq + MSZ;
  half_t* Mv = Mk + MSZ;
  half_t* Mo = Mv + MSZ;

  prep_kernel<<<18432, 256, 0, stream>>>(query, key, value, xq, xk, xv, Wq, Aq,
                                         Wk, Ak, Wv, Av, Wo, Mq, Mk, Mv, Mo);

  dim3 gq(D / 128, NROWS / 64, 3);  // (6, 64, 3) = 1152 blocks
  gemm_qkv_kernel<<<gq, 256, 0, stream>>>(xq, xk, xv, Mq, Mk, Mv, bq, bk, bv,
                                          qh, kh, vt);

  dim3 ga(S / 64, H, B_);  // (32, 12, 2)
  attn_mfma_kernel<<<ga, 512, 0, stream>>>(qh, kh, vt, ab);

  dim3 go(D / 64, NROWS / 64, 1);  // (12, 64) = 768 blocks
  gemm_o_kernel<<<go, 256, 0, stream>>>(ab, Mo, bo, out);
}

// Round 12
// 219.570 us; speedup vs baseline: 1.5923x; 1.0159x over previous
//
#include <hip/hip_runtime.h>
#include <math.h>
#include <stdint.h>

// Problem constants
#define D 768
#define S 2048
#define B_ 2
#define NROWS 4096   // B_*S
#define H 12
#define HD 64
#define R_ 16

typedef _Float16 half_t;
typedef _Float16 half8 __attribute__((ext_vector_type(8)));
typedef _Float16 half4 __attribute__((ext_vector_type(4)));
typedef float floatx4 __attribute__((ext_vector_type(4)));

#define MFMA32(a, b, c) __builtin_amdgcn_mfma_f32_16x16x32_f16(a, b, c, 0, 0, 0)
#define MFMA16(a, b, c) __builtin_amdgcn_mfma_f32_16x16x16f16(a, b, c, 0, 0, 0)
#define EXP2F(x) __builtin_amdgcn_exp2f(x)

// s_waitcnt vmcnt(N) (lgkm/exp unconstrained) + raw workgroup barrier.
// This is the cp.async.wait_group analog: with 3 LDS stages, the end-of-iter
// wait retires the stage issued a FULL iteration ago, never the fresh one.
#define SWAIT(N) __builtin_amdgcn_s_waitcnt(0x0F70 | (N))
#define SBAR() __builtin_amdgcn_s_barrier()

// global -> LDS async DMA, 16B per lane; lane i lands at base + 16*i.
__device__ __forceinline__ void gl_lds16(const void* gp, half_t* lp) {
  __builtin_amdgcn_global_load_lds(
      (const __attribute__((address_space(1))) void*)(gp),
      (__attribute__((address_space(3))) void*)(lp), 16, 0, 0);
}

// V^T tiled-fragment layout ("vt2"): per head bh = b*H+h, per 64-token block
// kb (32 blocks): 4096 halfs = groups (ud 0..3, h2 0..1) x 512 halfs; lane
// (lq,lr) holds 8 halfs: V[kb*64+32*h2+lq*4+{0..3}][ud*16+lr] ++
//                        V[kb*64+32*h2+16+lq*4+{0..3}][ud*16+lr].

// ---------------------------------------------------------------------------
// Fused prep: blocks [0, 9216): fp32->fp16 convert of q,k,v.
//             blocks [9216, 18432): build folded LoRA weights
//             Mh[j][k] = W[j][k] + 4*sum_r A[k,r]A[j,r]  (fp16, [j][k]).
// ---------------------------------------------------------------------------
__global__ __launch_bounds__(256) void prep_kernel(
    const float* __restrict__ q, const float* __restrict__ k,
    const float* __restrict__ v, half_t* __restrict__ xq,
    half_t* __restrict__ xk, half_t* __restrict__ xv,
    const float* __restrict__ Wq, const float* __restrict__ Aq,
    const float* __restrict__ Wk, const float* __restrict__ Ak,
    const float* __restrict__ Wv, const float* __restrict__ Av,
    const float* __restrict__ Wo, half_t* __restrict__ Mq,
    half_t* __restrict__ Mk, half_t* __restrict__ Mv,
    half_t* __restrict__ Mo) {
  const int bid = blockIdx.x;
  if (bid < 9216) {
    const int y = bid / 3072;
    const float* x = (y == 0) ? q : (y == 1) ? k : v;
    half_t* o = (y == 0) ? xq : (y == 1) ? xk : xv;
    int i = (bid - y * 3072) * 1024 + threadIdx.x * 4;
    float4 vv = *reinterpret_cast<const float4*>(x + i);
    half_t tmp[4] = {(half_t)vv.x, (half_t)vv.y, (half_t)vv.z, (half_t)vv.w};
    *reinterpret_cast<uint64_t*>(o + i) = *reinterpret_cast<uint64_t*>(tmp);
  } else {
    const int u = bid - 9216;
    const int y = u / 2304;
    const float* W = (y == 0) ? Wq : (y == 1) ? Wk : (y == 2) ? Wv : Wo;
    const float* A = (y == 0) ? Aq : (y == 1) ? Ak : (y == 2) ? Av : nullptr;
    half_t* M = (y == 0) ? Mq : (y == 1) ? Mk : (y == 2) ? Mv : Mo;
    int idx = (u - y * 2304) * 256 + threadIdx.x;  // j*768 + k
    int j = idx / D;
    int kk = idx - j * D;
    float acc = W[idx];
    if (A != nullptr) {
      float s = 0.f;
#pragma unroll
      for (int r = 0; r < R_; ++r) s += A[kk * R_ + r] * A[j * R_ + r];
      acc += 4.0f * s;
    }
    M[idx] = (half_t)acc;
  }
}

// ---------------------------------------------------------------------------
// QKV GEMM (fp16 in/out): C[n][j] = sum_k X[n][k]*Mh[j][k] + bias[j].
// 64x128 tile, 4 waves (1x4), BK=64, 3-stage DMA pipeline (72KB LDS),
// raw barrier + vmcnt(6) per iter (never drains the fresh stage).
// z==2 writes V output in vt2 layout via direct coalesced half4 stores.
// ---------------------------------------------------------------------------
__global__ __launch_bounds__(256) void gemm_qkv_kernel(
    const half_t* __restrict__ x0, const half_t* __restrict__ x1,
    const half_t* __restrict__ x2, const half_t* __restrict__ m0,
    const half_t* __restrict__ m1, const half_t* __restrict__ m2,
    const float* __restrict__ b0, const float* __restrict__ b1,
    const float* __restrict__ b2, half_t* __restrict__ o0,
    half_t* __restrict__ o1, half_t* __restrict__ o2) {
  constexpr int AG = 8;        // A groups (64 rows x 64 k)
  constexpr int G = AG + 16;   // + B groups (128 cols x 64 k)
  constexpr int PB = G * 512;  // 12288 halfs = 24KB per stage
  __shared__ __align__(16) half_t smem[3 * PB];  // 72KB

  const int z = blockIdx.z;
  const half_t* X = (z == 0) ? x0 : (z == 1) ? x1 : x2;
  const half_t* M = (z == 0) ? m0 : (z == 1) ? m1 : m2;
  const float* bias = (z == 0) ? b0 : (z == 1) ? b1 : b2;
  half_t* Out = (z == 0) ? o0 : (z == 1) ? o1 : o2;

  const int tid = threadIdx.x;
  const int lane = tid & 63;
  const int wv = tid >> 6;
  const int lr = lane & 15;
  const int lq = lane >> 4;
  const int row0 = blockIdx.y * 64;
  const int j0 = blockIdx.x * 128;
  const int wc = wv;  // 1x4 wave grid, 32 cols per wave

  floatx4 acc[4][2] = {};

#define GSTAGE(soff, k0)                                                       \
  do {                                                                         \
    _Pragma("unroll") for (int gi = 0; gi < 6; ++gi) {                         \
      int g = wv * 6 + gi;                                                     \
      if (g < AG) {                                                            \
        int t = g >> 1, c = g & 1;                                             \
        gl_lds16(                                                              \
            X + (size_t)(row0 + t * 16 + lr) * D + (k0) + c * 32 + lq * 8,     \
            smem + (soff) + g * 512);                                          \
      } else {                                                                 \
        int g2 = g - AG;                                                       \
        int u = g2 >> 1, c = g2 & 1;                                           \
        gl_lds16(                                                              \
            M + (size_t)(j0 + u * 16 + lr) * D + (k0) + c * 32 + lq * 8,       \
            smem + (soff) + AG * 512 + g2 * 512);                              \
      }                                                                        \
    }                                                                          \
  } while (0)

  GSTAGE(0, 0);
  GSTAGE(PB, 64);
  SWAIT(6);  // stage 0 resident (only stage 1's 6 DMAs may remain)
  SBAR();

  int co = 0, so = 2 * PB;
  for (int it = 0; it < D / 64; ++it) {
    if (it + 2 < D / 64) GSTAGE(so, (it + 2) * 64);
    const half_t* Ab = smem + co;
    const half_t* Bb = Ab + AG * 512;
#pragma unroll
    for (int c = 0; c < 2; ++c) {
      half8 af[4], bf[2];
#pragma unroll
      for (int t = 0; t < 4; ++t)
        af[t] = *reinterpret_cast<const half8*>(
            &Ab[((t * 2 + c) * 64 + lane) * 8]);
#pragma unroll
      for (int u = 0; u < 2; ++u)
        bf[u] = *reinterpret_cast<const half8*>(
            &Bb[(((wc * 2 + u) * 2 + c) * 64 + lane) * 8]);
#pragma unroll
      for (int t = 0; t < 4; ++t)
#pragma unroll
        for (int u = 0; u < 2; ++u) acc[t][u] = MFMA32(af[t], bf[u], acc[t][u]);
    }
    if (it + 2 < D / 64) SWAIT(6); else SWAIT(0);
    SBAR();
    co += PB; if (co == 3 * PB) co = 0;
    so += PB; if (so == 3 * PB) so = 0;
  }
#undef GSTAGE

  float bv[2];
#pragma unroll
  for (int u = 0; u < 2; ++u) bv[u] = bias[j0 + (wc * 2 + u) * 16 + lr];

  if (z == 2) {
    // Direct vt2 stores from registers
    const int bb = row0 >> 11;
    const int kb = (row0 & 2047) >> 6;
#pragma unroll
    for (int t = 0; t < 4; ++t) {
#pragma unroll
      for (int u = 0; u < 2; ++u) {
        int gc = j0 + (wc * 2 + u) * 16 + lr;
        int hh = gc >> 6;
        int ud = (wc * 2 + u) & 3;
        half4 hv;
#pragma unroll
        for (int r = 0; r < 4; ++r) hv[r] = (half_t)(acc[t][u][r] + bv[u]);
        size_t addr = ((size_t)(bb * H + hh) * HD) * S + (size_t)kb * 4096 +
                      (ud * 2 + (t >> 1)) * 512 + lane * 8 + (t & 1) * 4;
        *reinterpret_cast<half4*>(&Out[addr]) = hv;
      }
    }
    return;
  }

#pragma unroll
  for (int t = 0; t < 4; ++t) {
#pragma unroll
    for (int u = 0; u < 2; ++u) {
#pragma unroll
      for (int r = 0; r < 4; ++r) {
        int gr = row0 + t * 16 + lq * 4 + r;
        int gc = j0 + (wc * 2 + u) * 16 + lr;
        Out[(size_t)gr * D + gc] = (half_t)(acc[t][u][r] + bv[u]);
      }
    }
  }
}

// ---------------------------------------------------------------------------
// Out-projection GEMM (fp16 in, fp32 out): 64x64 tile, 4 waves (2x2),
// 3-stage DMA pipeline (48KB LDS), raw barrier + vmcnt(4) per iter.
// ---------------------------------------------------------------------------
__global__ __launch_bounds__(256) void gemm_o_kernel(
    const half_t* __restrict__ Xh, const half_t* __restrict__ M,
    const float* __restrict__ bias, float* __restrict__ Out) {
  constexpr int AG = 8;        // A groups (64 rows)
  constexpr int G = 16;        // + 8 B groups (64 cols)
  constexpr int PB = G * 512;  // 8192 halfs = 16KB per stage
  __shared__ __align__(16) half_t smem[3 * PB];  // 48KB

  const int tid = threadIdx.x;
  const int lane = tid & 63;
  const int wv = tid >> 6;
  const int lr = lane & 15;
  const int lq = lane >> 4;
  const int row0 = blockIdx.y * 64;
  const int j0 = blockIdx.x * 64;
  const int wr = wv >> 1;  // wave row 0..1
  const int wc = wv & 1;   // wave col 0..1

  floatx4 acc[2][2] = {};

#define GSTAGE(soff, k0)                                                       \
  do {                                                                         \
    _Pragma("unroll") for (int gi = 0; gi < 4; ++gi) {                         \
      int g = wv * 4 + gi;                                                     \
      if (g < AG) {                                                            \
        int t = g >> 1, c = g & 1;                                             \
        gl_lds16(                                                              \
            Xh + (size_t)(row0 + t * 16 + lr) * D + (k0) + c * 32 + lq * 8,    \
            smem + (soff) + g * 512);                                          \
      } else {                                                                 \
        int g2 = g - AG;                                                       \
        int u = g2 >> 1, c = g2 & 1;                                           \
        gl_lds16(                                                              \
            M + (size_t)(j0 + u * 16 + lr) * D + (k0) + c * 32 + lq * 8,       \
            smem + (soff) + AG * 512 + g2 * 512);                              \
      }                                                                        \
    }                                                                          \
  } while (0)

  GSTAGE(0, 0);
  GSTAGE(PB, 64);
  SWAIT(4);
  SBAR();

  int co = 0, so = 2 * PB;
  for (int it = 0; it < D / 64; ++it) {
    if (it + 2 < D / 64) GSTAGE(so, (it + 2) * 64);
    const half_t* Ab = smem + co;
    const half_t* Bb = Ab + AG * 512;
#pragma unroll
    for (int c = 0; c < 2; ++c) {
      half8 af[2], bf[2];
#pragma unroll
      for (int t = 0; t < 2; ++t)
        af[t] = *reinterpret_cast<const half8*>(
            &Ab[(((wr * 2 + t) * 2 + c) * 64 + lane) * 8]);
#pragma unroll
      for (int u = 0; u < 2; ++u)
        bf[u] = *reinterpret_cast<const half8*>(
            &Bb[(((wc * 2 + u) * 2 + c) * 64 + lane) * 8]);
#pragma unroll
      for (int t = 0; t < 2; ++t)
#pragma unroll
        for (int u = 0; u < 2; ++u) acc[t][u] = MFMA32(af[t], bf[u], acc[t][u]);
    }
    if (it + 2 < D / 64) SWAIT(4); else SWAIT(0);
    SBAR();
    co += PB; if (co == 3 * PB) co = 0;
    so += PB; if (so == 3 * PB) so = 0;
  }
#undef GSTAGE

  float bv[2];
#pragma unroll
  for (int u = 0; u < 2; ++u) bv[u] = bias[j0 + (wc * 2 + u) * 16 + lr];
#pragma unroll
  for (int t = 0; t < 2; ++t) {
#pragma unroll
    for (int u = 0; u < 2; ++u) {
#pragma unroll
      for (int r = 0; r < 4; ++r) {
        int gr = row0 + (wr * 2 + t) * 16 + lq * 4 + r;
        int gc = j0 + (wc * 2 + u) * 16 + lr;
        Out[(size_t)gr * D + gc] = acc[t][u][r] + bv[u];
      }
    }
  }
}

// ---------------------------------------------------------------------------
// Flash attention, in-block split-K. 512 threads (8 waves), 64 q-rows/block.
// Wave w: q-subtile t=w&3 (16 rows), k'-half = w>>2 (2 of 4 u-tiles/iter).
// 3-stage DMA pipeline (48KB LDS), raw barrier + vmcnt(2) per iter.
// K LDS-staged in B-frag order; V in vt2 interleaved layout (b128 reads).
// Partials additive (no running max); merged once at the end via LDS.
// ---------------------------------------------------------------------------
__global__ __launch_bounds__(512, 6) void attn_mfma_kernel(
    const half_t* __restrict__ Qh, const half_t* __restrict__ Kh,
    const half_t* __restrict__ Vt2, half_t* __restrict__ Oh) {
  __shared__ __align__(16) half_t smem[24576];  // 48KB
  half_t* Ks = smem;            // 3 stages x 4096 halfs
  half_t* Vs = smem + 12288;    // 3 stages x 4096 halfs

  const int tid = threadIdx.x;
  const int lane = tid & 63;
  const int wv = tid >> 6;       // 0..7
  const int t_ = wv & 3;         // q-subtile
  const int half_ = wv >> 2;     // k'-half
  const int lr = lane & 15;
  const int lq = lane >> 4;
  const int q0 = blockIdx.x * 64;
  const int h = blockIdx.y;
  const int b = blockIdx.z;
  const size_t base = (size_t)b * S * D + h * HD;              // + row*D
  const size_t vtbase = (size_t)(b * H + h) * HD * (size_t)S;  // vt2 head base
  const int qw = q0 + t_ * 16;

  // Q B-fragments, scale = (1/8)*log2(e) -> exp2 later
  const half_t qscale = (half_t)0.18033688f;
  half8 qf[2];
#pragma unroll
  for (int c = 0; c < 2; ++c) {
    half8 qv = *reinterpret_cast<const half8*>(
        &Qh[base + (size_t)(qw + lr) * D + c * 32 + lq * 8]);
#pragma unroll
    for (int j = 0; j < 8; ++j) qv[j] = qv[j] * qscale;
    qf[c] = qv;
  }

  half4 ones;
#pragma unroll
  for (int j = 0; j < 4; ++j) ones[j] = (half_t)1.0f;

  floatx4 o[4] = {};
  floatx4 ol = {};

  // 16 DMA groups (8 K + 8 V), 2 per wave.
#define STAGE(soff, kb)                                                        \
  do {                                                                         \
    _Pragma("unroll") for (int gi = 0; gi < 2; ++gi) {                         \
      int g = wv * 2 + gi;                                                     \
      if (g < 8) {                                                             \
        int u = g >> 1, c = g & 1;                                             \
        gl_lds16(                                                              \
            Kh + base + (size_t)((kb) + u * 16 + lr) * D + c * 32 + lq * 8,    \
            Ks + (soff) + g * 512);                                            \
      } else {                                                                 \
        int gv = g - 8;                                                        \
        gl_lds16(Vt2 + vtbase + (size_t)(kb)*64 + gv * 512 + lane * 8,         \
                 Vs + (soff) + gv * 512);                                      \
      }                                                                        \
    }                                                                          \
  } while (0)

  STAGE(0, 0);
  STAGE(4096, 64);
  SWAIT(2);
  SBAR();

  int co = 0, so = 8192;
  for (int it = 0; it < S / 64; ++it) {
    if (it + 2 < S / 64) STAGE(so, (it + 2) * 64);

    // S^T for both u-subtiles of this wave's k'-half
    half4 pf[2];
#pragma unroll
    for (int ui = 0; ui < 2; ++ui) {
      const int u = half_ * 2 + ui;
      half8 kf0 = *reinterpret_cast<const half8*>(
          &Ks[co + ((u * 2 + 0) * 64 + lane) * 8]);
      half8 kf1 = *reinterpret_cast<const half8*>(
          &Ks[co + ((u * 2 + 1) * 64 + lane) * 8]);
      floatx4 st = {};
      st = MFMA32(kf0, qf[0], st);
      st = MFMA32(kf1, qf[1], st);
      pf[ui][0] = (half_t)EXP2F(st[0]);
      pf[ui][1] = (half_t)EXP2F(st[1]);
      pf[ui][2] = (half_t)EXP2F(st[2]);
      pf[ui][3] = (half_t)EXP2F(st[3]);
    }
    // PV: one b128 per ud supplies both u-subtile B-fragments
#pragma unroll
    for (int ud = 0; ud < 4; ++ud) {
      half8 vf8 = *reinterpret_cast<const half8*>(
          &Vs[co + ((ud * 2 + half_) * 64 + lane) * 8]);
      half4 vlo, vhi;
#pragma unroll
      for (int j = 0; j < 4; ++j) {
        vlo[j] = vf8[j];
        vhi[j] = vf8[4 + j];
      }
      o[ud] = MFMA16(pf[0], vlo, o[ud]);
      o[ud] = MFMA16(pf[1], vhi, o[ud]);
    }
    ol = MFMA16(pf[0], ones, ol);
    ol = MFMA16(pf[1], ones, ol);

    if (it + 2 < S / 64) SWAIT(2); else SWAIT(0);
    SBAR();
    co += 4096; if (co == 12288) co = 0;
    so += 4096; if (so == 12288) so = 0;
  }
#undef STAGE

  // merge k'-halves: waves 4-7 deposit partials (SoA, stride 260), 0-3 reduce
  float* red = (float*)smem;  // 20 comps x 260 floats = 20.8KB <= 48KB
  const int slot = t_ * 64 + lane;  // 0..255
  if (half_ == 1) {
#pragma unroll
    for (int comp = 0; comp < 16; ++comp)
      red[comp * 260 + slot] = o[comp >> 2][comp & 3];
#pragma unroll
    for (int r = 0; r < 4; ++r) red[(16 + r) * 260 + slot] = ol[r];
  }
  __syncthreads();
  if (half_ == 0) {
#pragma unroll
    for (int comp = 0; comp < 16; ++comp)
      o[comp >> 2][comp & 3] += red[comp * 260 + slot];
    float linv[4];
#pragma unroll
    for (int r = 0; r < 4; ++r)
      linv[r] = 1.0f / (ol[r] + red[(16 + r) * 260 + slot]);
#pragma unroll
    for (int ud = 0; ud < 4; ++ud) {
#pragma unroll
      for (int r = 0; r < 4; ++r) {
        int row = qw + lq * 4 + r;
        int col = h * HD + ud * 16 + lr;
        Oh[(size_t)(b * S + row) * D + col] = (half_t)(o[ud][r] * linv[r]);
      }
    }
  }
}

// ---------------------------------------------------------------------------
// Launch
// ---------------------------------------------------------------------------
extern "C" void kernel_launch(void* const* d_in, const int* in_sizes, int n_in,
                              void* d_out, int out_size, void* d_ws,
                              size_t ws_size, hipStream_t stream) {
  const float* query = (const float*)d_in[0];
  const float* key   = (const float*)d_in[1];
  const float* value = (const float*)d_in[2];
  const float* Wq = (const float*)d_in[3];
  const float* bq = (const float*)d_in[4];
  const float* Aq = (const float*)d_in[5];
  const float* Wk = (const float*)d_in[6];
  const float* bk = (const float*)d_in[7];
  const float* Ak = (const float*)d_in[8];
  const float* Wv = (const float*)d_in[9];
  const float* bv = (const float*)d_in[10];
  const float* Av = (const float*)d_in[11];
  const float* Wo = (const float*)d_in[12];
  const float* bo = (const float*)d_in[13];
  float* out = (float*)d_out;

  half_t* hw = (half_t*)d_ws;
  const size_t XSZ = (size_t)NROWS * D;  // 3145728
  const size_t MSZ = (size_t)D * D;      // 589824
  half_t* xq = hw;              // converted inputs (fp16)
  half_t* xk = xq + XSZ;
  half_t* xv = xk + XSZ;
  half_t* qh = xv + XSZ;        // Q projection [n][D]
  half_t* kh = qh + XSZ;        // K projection [n][D]
  half_t* vt = kh + XSZ;        // V projection, vt2 tiled-fragment layout
  half_t* ab = vt + XSZ;        // attention output [n][D]
  half_t* Mq = ab + XSZ;
  half_t* Mk = Mq + MSZ;
  half_t* Mv = Mk + MSZ;
  half_t* Mo = Mv + MSZ;

  prep_kernel<<<18432, 256, 0, stream>>>(query, key, value, xq, xk, xv, Wq, Aq,
                                         Wk, Ak, Wv, Av, Wo, Mq, Mk, Mv, Mo);

  dim3 gq(D / 128, NROWS / 64, 3);  // (6, 64, 3) = 1152 blocks
  gemm_qkv_kernel<<<gq, 256, 0, stream>>>(xq, xk, xv, Mq, Mk, Mv, bq, bk, bv,
                                          qh, kh, vt);

  dim3 ga(S / 64, H, B_);  // (32, 12, 2)
  attn_mfma_kernel<<<ga, 512, 0, stream>>>(qh, kh, vt, ab);

  dim3 go(D / 64, NROWS / 64, 1);  // (12, 64) = 768 blocks
  gemm_o_kernel<<<go, 256, 0, stream>>>(ab, Mo, bo, out);
}

// Round 13
// 218.781 us; speedup vs baseline: 1.5980x; 1.0036x over previous
//
#include <hip/hip_runtime.h>
#include <math.h>
#include <stdint.h>

// Problem constants
#define D 768
#define S 2048
#define B_ 2
#define NROWS 4096   // B_*S
#define H 12
#define HD 64
#define R_ 16

typedef _Float16 half_t;
typedef _Float16 half8 __attribute__((ext_vector_type(8)));
typedef _Float16 half4 __attribute__((ext_vector_type(4)));
typedef float floatx4 __attribute__((ext_vector_type(4)));

#define MFMA32(a, b, c) __builtin_amdgcn_mfma_f32_16x16x32_f16(a, b, c, 0, 0, 0)
#define MFMA16(a, b, c) __builtin_amdgcn_mfma_f32_16x16x16f16(a, b, c, 0, 0, 0)
#define EXP2F(x) __builtin_amdgcn_exp2f(x)

#define SWAIT(N) __builtin_amdgcn_s_waitcnt(0x0F70 | (N))
#define SBAR() __builtin_amdgcn_s_barrier()

// global -> LDS async DMA, 16B per lane; lane i lands at base + 16*i.
__device__ __forceinline__ void gl_lds16(const void* gp, half_t* lp) {
  __builtin_amdgcn_global_load_lds(
      (const __attribute__((address_space(1))) void*)(gp),
      (__attribute__((address_space(3))) void*)(lp), 16, 0, 0);
}

// V^T tiled-fragment layout ("vt2"): per head bh = b*H+h, per 64-token block
// kb (32 blocks): 4096 halfs = groups (ud 0..3, h2 0..1) x 512 halfs; lane
// (lq,lr) holds 8 halfs: V[kb*64+32*h2+lq*4+{0..3}][ud*16+lr] ++
//                        V[kb*64+32*h2+16+lq*4+{0..3}][ud*16+lr].

// ---------------------------------------------------------------------------
// Fused prep: blocks [0, 9216): fp32->fp16 convert of q,k,v.
//             blocks [9216, 18432): build folded LoRA weights
//             Mh[j][k] = W[j][k] + 4*sum_r A[k,r]A[j,r]  (fp16, [j][k]).
// ---------------------------------------------------------------------------
__global__ __launch_bounds__(256) void prep_kernel(
    const float* __restrict__ q, const float* __restrict__ k,
    const float* __restrict__ v, half_t* __restrict__ xq,
    half_t* __restrict__ xk, half_t* __restrict__ xv,
    const float* __restrict__ Wq, const float* __restrict__ Aq,
    const float* __restrict__ Wk, const float* __restrict__ Ak,
    const float* __restrict__ Wv, const float* __restrict__ Av,
    const float* __restrict__ Wo, half_t* __restrict__ Mq,
    half_t* __restrict__ Mk, half_t* __restrict__ Mv,
    half_t* __restrict__ Mo) {
  const int bid = blockIdx.x;
  if (bid < 9216) {
    const int y = bid / 3072;
    const float* x = (y == 0) ? q : (y == 1) ? k : v;
    half_t* o = (y == 0) ? xq : (y == 1) ? xk : xv;
    int i = (bid - y * 3072) * 1024 + threadIdx.x * 4;
    float4 vv = *reinterpret_cast<const float4*>(x + i);
    half_t tmp[4] = {(half_t)vv.x, (half_t)vv.y, (half_t)vv.z, (half_t)vv.w};
    *reinterpret_cast<uint64_t*>(o + i) = *reinterpret_cast<uint64_t*>(tmp);
  } else {
    const int u = bid - 9216;
    const int y = u / 2304;
    const float* W = (y == 0) ? Wq : (y == 1) ? Wk : (y == 2) ? Wv : Wo;
    const float* A = (y == 0) ? Aq : (y == 1) ? Ak : (y == 2) ? Av : nullptr;
    half_t* M = (y == 0) ? Mq : (y == 1) ? Mk : (y == 2) ? Mv : Mo;
    int idx = (u - y * 2304) * 256 + threadIdx.x;  // j*768 + k
    int j = idx / D;
    int kk = idx - j * D;
    float acc = W[idx];
    if (A != nullptr) {
      float s = 0.f;
#pragma unroll
      for (int r = 0; r < R_; ++r) s += A[kk * R_ + r] * A[j * R_ + r];
      acc += 4.0f * s;
    }
    M[idx] = (half_t)acc;
  }
}

// ---------------------------------------------------------------------------
// QKV GEMM (fp16 in/out): C[n][j] = sum_k X[n][k]*Mh[j][k] + bias[j].
// 128x128 tile, 4 waves (2x2, 64x64 each), BK=64, 2-stage DMA double-buffer
// (64KB LDS), one __syncthreads per iter. 32 MFMA : 16 b128-reads per
// wave-iter (m97 shape -- 3x the MFMA-per-LDS-byte of the 64x128 form).
// z==2 writes V output in vt2 layout via direct coalesced half4 stores.
// ---------------------------------------------------------------------------
__global__ __launch_bounds__(256) void gemm_qkv_kernel(
    const half_t* __restrict__ x0, const half_t* __restrict__ x1,
    const half_t* __restrict__ x2, const half_t* __restrict__ m0,
    const half_t* __restrict__ m1, const half_t* __restrict__ m2,
    const float* __restrict__ b0, const float* __restrict__ b1,
    const float* __restrict__ b2, half_t* __restrict__ o0,
    half_t* __restrict__ o1, half_t* __restrict__ o2) {
  constexpr int AG = 16;       // A groups (128 rows x 64 k)
  constexpr int G = AG + 16;   // + B groups (128 cols x 64 k)
  constexpr int PB = G * 512;  // 16384 halfs = 32KB per stage
  __shared__ __align__(16) half_t smem[2 * PB];  // 64KB

  const int z = blockIdx.z;
  const half_t* X = (z == 0) ? x0 : (z == 1) ? x1 : x2;
  const half_t* M = (z == 0) ? m0 : (z == 1) ? m1 : m2;
  const float* bias = (z == 0) ? b0 : (z == 1) ? b1 : b2;
  half_t* Out = (z == 0) ? o0 : (z == 1) ? o1 : o2;

  const int tid = threadIdx.x;
  const int lane = tid & 63;
  const int wv = tid >> 6;
  const int lr = lane & 15;
  const int lq = lane >> 4;
  const int row0 = blockIdx.y * 128;
  const int j0 = blockIdx.x * 128;
  const int wr = wv >> 1;  // wave row 0..1
  const int wc = wv & 1;   // wave col 0..1

  floatx4 acc[4][4] = {};

#define GSTAGE(bufi, k0)                                                       \
  do {                                                                         \
    _Pragma("unroll") for (int gi = 0; gi < 8; ++gi) {                         \
      int g = wv * 8 + gi;                                                     \
      if (g < AG) {                                                            \
        int t = g >> 1, c = g & 1;                                             \
        gl_lds16(                                                              \
            X + (size_t)(row0 + t * 16 + lr) * D + (k0) + c * 32 + lq * 8,     \
            smem + (bufi)*PB + g * 512);                                       \
      } else {                                                                 \
        int g2 = g - AG;                                                       \
        int u = g2 >> 1, c = g2 & 1;                                           \
        gl_lds16(                                                              \
            M + (size_t)(j0 + u * 16 + lr) * D + (k0) + c * 32 + lq * 8,       \
            smem + (bufi)*PB + AG * 512 + g2 * 512);                           \
      }                                                                        \
    }                                                                          \
  } while (0)

  GSTAGE(0, 0);
  __syncthreads();

  for (int it = 0; it < D / 64; ++it) {
    const int cur = it & 1;
    if (it + 1 < D / 64) GSTAGE(cur ^ 1, (it + 1) * 64);
    const half_t* Ab = smem + cur * PB;
    const half_t* Bb = Ab + AG * 512;
#pragma unroll
    for (int c = 0; c < 2; ++c) {
      half8 af[4], bf[4];
#pragma unroll
      for (int t = 0; t < 4; ++t)
        af[t] = *reinterpret_cast<const half8*>(
            &Ab[(((wr * 4 + t) * 2 + c) * 64 + lane) * 8]);
#pragma unroll
      for (int u = 0; u < 4; ++u)
        bf[u] = *reinterpret_cast<const half8*>(
            &Bb[(((wc * 4 + u) * 2 + c) * 64 + lane) * 8]);
#pragma unroll
      for (int t = 0; t < 4; ++t)
#pragma unroll
        for (int u = 0; u < 4; ++u) acc[t][u] = MFMA32(af[t], bf[u], acc[t][u]);
    }
    __syncthreads();
  }
#undef GSTAGE

  float bv[4];
#pragma unroll
  for (int u = 0; u < 4; ++u) bv[u] = bias[j0 + (wc * 4 + u) * 16 + lr];

  if (z == 2) {
    // Direct vt2 stores from registers. Rows span 2 kb-blocks: kb = wr.
    // token T0 = row0 + (wr*4+t)*16 + lq*4 -> lq slot = lq, half = t&1,
    // h2 = (t>>1)&1, kb_local = wr.
    const int bb = row0 >> 11;
    const int kb0 = (row0 & 2047) >> 6;
#pragma unroll
    for (int t = 0; t < 4; ++t) {
#pragma unroll
      for (int u = 0; u < 4; ++u) {
        int gc = j0 + (wc * 4 + u) * 16 + lr;
        int hh = gc >> 6;
        int ud = (gc & 63) >> 4;
        half4 hv;
#pragma unroll
        for (int r = 0; r < 4; ++r) hv[r] = (half_t)(acc[t][u][r] + bv[u]);
        size_t addr = ((size_t)(bb * H + hh) * HD) * S +
                      (size_t)(kb0 + wr) * 4096 +
                      (ud * 2 + ((t >> 1) & 1)) * 512 + lane * 8 + (t & 1) * 4;
        *reinterpret_cast<half4*>(&Out[addr]) = hv;
      }
    }
    return;
  }

#pragma unroll
  for (int t = 0; t < 4; ++t) {
#pragma unroll
    for (int u = 0; u < 4; ++u) {
#pragma unroll
      for (int r = 0; r < 4; ++r) {
        int gr = row0 + (wr * 4 + t) * 16 + lq * 4 + r;
        int gc = j0 + (wc * 4 + u) * 16 + lr;
        Out[(size_t)gr * D + gc] = (half_t)(acc[t][u][r] + bv[u]);
      }
    }
  }
}

// ---------------------------------------------------------------------------
// Out-projection GEMM (fp16 in, fp32 out): 64x64 tile, 4 waves (2x2),
// 3-stage DMA pipeline (48KB LDS), raw barrier + vmcnt(4) per iter.
// ---------------------------------------------------------------------------
__global__ __launch_bounds__(256) void gemm_o_kernel(
    const half_t* __restrict__ Xh, const half_t* __restrict__ M,
    const float* __restrict__ bias, float* __restrict__ Out) {
  constexpr int AG = 8;        // A groups (64 rows)
  constexpr int G = 16;        // + 8 B groups (64 cols)
  constexpr int PB = G * 512;  // 8192 halfs = 16KB per stage
  __shared__ __align__(16) half_t smem[3 * PB];  // 48KB

  const int tid = threadIdx.x;
  const int lane = tid & 63;
  const int wv = tid >> 6;
  const int lr = lane & 15;
  const int lq = lane >> 4;
  const int row0 = blockIdx.y * 64;
  const int j0 = blockIdx.x * 64;
  const int wr = wv >> 1;  // wave row 0..1
  const int wc = wv & 1;   // wave col 0..1

  floatx4 acc[2][2] = {};

#define GSTAGE(soff, k0)                                                       \
  do {                                                                         \
    _Pragma("unroll") for (int gi = 0; gi < 4; ++gi) {                         \
      int g = wv * 4 + gi;                                                     \
      if (g < AG) {                                                            \
        int t = g >> 1, c = g & 1;                                             \
        gl_lds16(                                                              \
            Xh + (size_t)(row0 + t * 16 + lr) * D + (k0) + c * 32 + lq * 8,    \
            smem + (soff) + g * 512);                                          \
      } else {                                                                 \
        int g2 = g - AG;                                                       \
        int u = g2 >> 1, c = g2 & 1;                                           \
        gl_lds16(                                                              \
            M + (size_t)(j0 + u * 16 + lr) * D + (k0) + c * 32 + lq * 8,       \
            smem + (soff) + AG * 512 + g2 * 512);                              \
      }                                                                        \
    }                                                                          \
  } while (0)

  GSTAGE(0, 0);
  GSTAGE(PB, 64);
  SWAIT(4);
  SBAR();

  int co = 0, so = 2 * PB;
  for (int it = 0; it < D / 64; ++it) {
    if (it + 2 < D / 64) GSTAGE(so, (it + 2) * 64);
    const half_t* Ab = smem + co;
    const half_t* Bb = Ab + AG * 512;
#pragma unroll
    for (int c = 0; c < 2; ++c) {
      half8 af[2], bf[2];
#pragma unroll
      for (int t = 0; t < 2; ++t)
        af[t] = *reinterpret_cast<const half8*>(
            &Ab[(((wr * 2 + t) * 2 + c) * 64 + lane) * 8]);
#pragma unroll
      for (int u = 0; u < 2; ++u)
        bf[u] = *reinterpret_cast<const half8*>(
            &Bb[(((wc * 2 + u) * 2 + c) * 64 + lane) * 8]);
#pragma unroll
      for (int t = 0; t < 2; ++t)
#pragma unroll
        for (int u = 0; u < 2; ++u) acc[t][u] = MFMA32(af[t], bf[u], acc[t][u]);
    }
    if (it + 2 < D / 64) SWAIT(4); else SWAIT(0);
    SBAR();
    co += PB; if (co == 3 * PB) co = 0;
    so += PB; if (so == 3 * PB) so = 0;
  }
#undef GSTAGE

  float bv[2];
#pragma unroll
  for (int u = 0; u < 2; ++u) bv[u] = bias[j0 + (wc * 2 + u) * 16 + lr];
#pragma unroll
  for (int t = 0; t < 2; ++t) {
#pragma unroll
    for (int u = 0; u < 2; ++u) {
#pragma unroll
      for (int r = 0; r < 4; ++r) {
        int gr = row0 + (wr * 2 + t) * 16 + lq * 4 + r;
        int gc = j0 + (wc * 2 + u) * 16 + lr;
        Out[(size_t)gr * D + gc] = acc[t][u][r] + bv[u];
      }
    }
  }
}

// ---------------------------------------------------------------------------
// Flash attention, in-block split-K. 512 threads (8 waves), 64 q-rows/block.
// Wave w: q-subtile t=w&3 (16 rows), k'-half = w>>2 (2 of 4 u-tiles/iter).
// 3-stage DMA pipeline (48KB LDS), raw barrier + vmcnt(2) per iter.
// K LDS-staged in B-frag order; V in vt2 interleaved layout (b128 reads).
// Partials additive (no running max); merged once at the end via LDS.
// ---------------------------------------------------------------------------
__global__ __launch_bounds__(512, 6) void attn_mfma_kernel(
    const half_t* __restrict__ Qh, const half_t* __restrict__ Kh,
    const half_t* __restrict__ Vt2, half_t* __restrict__ Oh) {
  __shared__ __align__(16) half_t smem[24576];  // 48KB
  half_t* Ks = smem;            // 3 stages x 4096 halfs
  half_t* Vs = smem + 12288;    // 3 stages x 4096 halfs

  const int tid = threadIdx.x;
  const int lane = tid & 63;
  const int wv = tid >> 6;       // 0..7
  const int t_ = wv & 3;         // q-subtile
  const int half_ = wv >> 2;     // k'-half
  const int lr = lane & 15;
  const int lq = lane >> 4;
  const int q0 = blockIdx.x * 64;
  const int h = blockIdx.y;
  const int b = blockIdx.z;
  const size_t base = (size_t)b * S * D + h * HD;              // + row*D
  const size_t vtbase = (size_t)(b * H + h) * HD * (size_t)S;  // vt2 head base
  const int qw = q0 + t_ * 16;

  // Q B-fragments, scale = (1/8)*log2(e) -> exp2 later
  const half_t qscale = (half_t)0.18033688f;
  half8 qf[2];
#pragma unroll
  for (int c = 0; c < 2; ++c) {
    half8 qv = *reinterpret_cast<const half8*>(
        &Qh[base + (size_t)(qw + lr) * D + c * 32 + lq * 8]);
#pragma unroll
    for (int j = 0; j < 8; ++j) qv[j] = qv[j] * qscale;
    qf[c] = qv;
  }

  half4 ones;
#pragma unroll
  for (int j = 0; j < 4; ++j) ones[j] = (half_t)1.0f;

  floatx4 o[4] = {};
  floatx4 ol = {};

  // 16 DMA groups (8 K + 8 V), 2 per wave.
#define STAGE(soff, kb)                                                        \
  do {                                                                         \
    _Pragma("unroll") for (int gi = 0; gi < 2; ++gi) {                         \
      int g = wv * 2 + gi;                                                     \
      if (g < 8) {                                                             \
        int u = g >> 1, c = g & 1;                                             \
        gl_lds16(                                                              \
            Kh + base + (size_t)((kb) + u * 16 + lr) * D + c * 32 + lq * 8,    \
            Ks + (soff) + g * 512);                                            \
      } else {                                                                 \
        int gv = g - 8;                                                        \
        gl_lds16(Vt2 + vtbase + (size_t)(kb)*64 + gv * 512 + lane * 8,         \
                 Vs + (soff) + gv * 512);                                      \
      }                                                                        \
    }                                                                          \
  } while (0)

  STAGE(0, 0);
  STAGE(4096, 64);
  SWAIT(2);
  SBAR();

  int co = 0, so = 8192;
  for (int it = 0; it < S / 64; ++it) {
    if (it + 2 < S / 64) STAGE(so, (it + 2) * 64);

    // S^T for both u-subtiles of this wave's k'-half
    half4 pf[2];
#pragma unroll
    for (int ui = 0; ui < 2; ++ui) {
      const int u = half_ * 2 + ui;
      half8 kf0 = *reinterpret_cast<const half8*>(
          &Ks[co + ((u * 2 + 0) * 64 + lane) * 8]);
      half8 kf1 = *reinterpret_cast<const half8*>(
          &Ks[co + ((u * 2 + 1) * 64 + lane) * 8]);
      floatx4 st = {};
      st = MFMA32(kf0, qf[0], st);
      st = MFMA32(kf1, qf[1], st);
      pf[ui][0] = (half_t)EXP2F(st[0]);
      pf[ui][1] = (half_t)EXP2F(st[1]);
      pf[ui][2] = (half_t)EXP2F(st[2]);
      pf[ui][3] = (half_t)EXP2F(st[3]);
    }
    // PV: one b128 per ud supplies both u-subtile B-fragments
#pragma unroll
    for (int ud = 0; ud < 4; ++ud) {
      half8 vf8 = *reinterpret_cast<const half8*>(
          &Vs[co + ((ud * 2 + half_) * 64 + lane) * 8]);
      half4 vlo, vhi;
#pragma unroll
      for (int j = 0; j < 4; ++j) {
        vlo[j] = vf8[j];
        vhi[j] = vf8[4 + j];
      }
      o[ud] = MFMA16(pf[0], vlo, o[ud]);
      o[ud] = MFMA16(pf[1], vhi, o[ud]);
    }
    ol = MFMA16(pf[0], ones, ol);
    ol = MFMA16(pf[1], ones, ol);

    if (it + 2 < S / 64) SWAIT(2); else SWAIT(0);
    SBAR();
    co += 4096; if (co == 12288) co = 0;
    so += 4096; if (so == 12288) so = 0;
  }
#undef STAGE

  // merge k'-halves: waves 4-7 deposit partials (SoA, stride 260), 0-3 reduce
  float* red = (float*)smem;  // 20 comps x 260 floats = 20.8KB <= 48KB
  const int slot = t_ * 64 + lane;  // 0..255
  if (half_ == 1) {
#pragma unroll
    for (int comp = 0; comp < 16; ++comp)
      red[comp * 260 + slot] = o[comp >> 2][comp & 3];
#pragma unroll
    for (int r = 0; r < 4; ++r) red[(16 + r) * 260 + slot] = ol[r];
  }
  __syncthreads();
  if (half_ == 0) {
#pragma unroll
    for (int comp = 0; comp < 16; ++comp)
      o[comp >> 2][comp & 3] += red[comp * 260 + slot];
    float linv[4];
#pragma unroll
    for (int r = 0; r < 4; ++r)
      linv[r] = 1.0f / (ol[r] + red[(16 + r) * 260 + slot]);
#pragma unroll
    for (int ud = 0; ud < 4; ++ud) {
#pragma unroll
      for (int r = 0; r < 4; ++r) {
        int row = qw + lq * 4 + r;
        int col = h * HD + ud * 16 + lr;
        Oh[(size_t)(b * S + row) * D + col] = (half_t)(o[ud][r] * linv[r]);
      }
    }
  }
}

// ---------------------------------------------------------------------------
// Launch
// ---------------------------------------------------------------------------
extern "C" void kernel_launch(void* const* d_in, const int* in_sizes, int n_in,
                              void* d_out, int out_size, void* d_ws,
                              size_t ws_size, hipStream_t stream) {
  const float* query = (const float*)d_in[0];
  const float* key   = (const float*)d_in[1];
  const float* value = (const float*)d_in[2];
  const float* Wq = (const float*)d_in[3];
  const float* bq = (const float*)d_in[4];
  const float* Aq = (const float*)d_in[5];
  const float* Wk = (const float*)d_in[6];
  const float* bk = (const float*)d_in[7];
  const float* Ak = (const float*)d_in[8];
  const float* Wv = (const float*)d_in[9];
  const float* bv = (const float*)d_in[10];
  const float* Av = (const float*)d_in[11];
  const float* Wo = (const float*)d_in[12];
  const float* bo = (const float*)d_in[13];
  float* out = (float*)d_out;

  half_t* hw = (half_t*)d_ws;
  const size_t XSZ = (size_t)NROWS * D;  // 3145728
  const size_t MSZ = (size_t)D * D;      // 589824
  half_t* xq = hw;              // converted inputs (fp16)
  half_t* xk = xq + XSZ;
  half_t* xv = xk + XSZ;
  half_t* qh = xv + XSZ;        // Q projection [n][D]
  half_t* kh = qh + XSZ;        // K projection [n][D]
  half_t* vt = kh + XSZ;        // V projection, vt2 tiled-fragment layout
  half_t* ab = vt + XSZ;        // attention output [n][D]
  half_t* Mq = ab + XSZ;
  half_t* Mk = Mq + MSZ;
  half_t* Mv = Mk + MSZ;
  half_t* Mo = Mv + MSZ;

  prep_kernel<<<18432, 256, 0, stream>>>(query, key, value, xq, xk, xv, Wq, Aq,
                                         Wk, Ak, Wv, Av, Wo, Mq, Mk, Mv, Mo);

  dim3 gq(D / 128, NROWS / 128, 3);  // (6, 32, 3) = 576 blocks
  gemm_qkv_kernel<<<gq, 256, 0, stream>>>(xq, xk, xv, Mq, Mk, Mv, bq, bk, bv,
                                          qh, kh, vt);

  dim3 ga(S / 64, H, B_);  // (32, 12, 2)
  attn_mfma_kernel<<<ga, 512, 0, stream>>>(qh, kh, vt, ab);

  dim3 go(D / 64, NROWS / 64, 1);  // (12, 64) = 768 blocks
  gemm_o_kernel<<<go, 256, 0, stream>>>(ab, Mo, bo, out);
}